// Round 12
// baseline (515.514 us; speedup 1.0000x reference)
//
#include <hip/hip_runtime.h>
#include <hip/hip_bf16.h>

typedef __bf16 bf16;
typedef __attribute__((ext_vector_type(4))) __bf16 bf16x4;
typedef __attribute__((ext_vector_type(8))) __bf16 bf16x8;
typedef __attribute__((ext_vector_type(4))) float floatx4;

constexpr int CB = 8, CS = 256, CD = 1024, CH = 16, CE = 4, CFF = 4096, CHD = 64;
constexpr long long DD  = 1048576;     // D*D
constexpr long long DFF = 4194304;     // D*FF
constexpr long long BSD = 2097152;     // B*S*D
constexpr long long PSD = 4194304;     // 16 pairs * 256 rows * 1024 (compact activation elems)

// ---------- workspace layout (bytes) ----------
constexpr size_t OFF_PART = 0;          // 64*1024 f32 (x column-sum partials)
constexpr size_t OFF_GATES= 262400;     // 32 f
constexpr size_t OFF_EACT = 262528;     // 4 int
constexpr size_t OFF_PBE  = 262592;     // 16 int: pair -> b | (e<<8)
constexpr size_t OFF_BP   = 262656;     // 16 int: batch -> 2 pair indices
constexpr size_t OFF_XBF  = 263168;     // BSD bf16
constexpr size_t OFF_WT   = OFF_XBF + (size_t)BSD*2;    // 16*DD bf16 (q,k,v,o x 4e), k-tile-blocked
constexpr size_t OFF_W1T  = OFF_WT  + (size_t)16*DD*2;  // 4*DFF bf16, k-tile-blocked
constexpr size_t OFF_W2T  = OFF_W1T + (size_t)4*DFF*2;  // 4*DFF bf16, k-tile-blocked
constexpr size_t OFF_QKV  = OFF_W2T + (size_t)4*DFF*2;  // 3*PSD bf16 (compact q,k,v)
constexpr size_t OFF_AO   = OFF_QKV + (size_t)3*PSD*2;  // PSD bf16
constexpr size_t OFF_F1   = OFF_QKV;                    // ALIAS: f1 (PSD*4 bf16) over qkv+ao (dead by FF1)
constexpr size_t OFF_PB   = OFF_AO  + (size_t)PSD*2;    // 2*PSD f32 (Wo partials) / 4*PSD bf16 (FF2 partials)
constexpr size_t OFF_VT   = OFF_PB;                     // ALIAS: vT (PSD bf16), dead before Wo writes PbF
constexpr size_t OFF_H    = OFF_PB  + (size_t)2*PSD*4;  // PSD f32
constexpr size_t OFF_HBF  = OFF_H   + (size_t)PSD*4;    // PSD bf16

// ---------- shared micro-transpose body: 2x2 wave super-tile, 8k x 8n per lane ----------
// Dest layout is K-TILE-BLOCKED: d[kt][n][64] with kt = k/64 (matches GEMM staging
// granularity). A wave's 64 lanes (8n x 8k) write 8 n-rows x 64 k = 1KB contiguous
// per store; the whole wave-tile is an 8KB contiguous span — no scattered writes.
__device__ __forceinline__ void wtile_trans(const float* __restrict__ src, bf16* __restrict__ d,
                                            int rows, int cols, int btk, int btn) {
  int w = threadIdx.x >> 6;
  int tk = btk*2 + (w & 1);
  int tn = btn*2 + (w >> 1);
  int lane = threadIdx.x & 63;
  int ln = lane >> 3, lk = lane & 7;  // lane = ln*8 + lk (lk fast -> contiguous k on store)
  int k0 = tk*64, n0 = tn*64;
  const float* s = src + (long long)(k0 + lk*8)*cols + n0 + ln*8;
  floatx4 f[8][2];
#pragma unroll
  for (int j = 0; j < 8; ++j) {
    f[j][0] = __builtin_nontemporal_load((const floatx4*)(s + (long long)j*cols));
    f[j][1] = __builtin_nontemporal_load((const floatx4*)(s + (long long)j*cols + 4));
  }
  bf16* dp = d + ((long long)tk*cols + n0 + ln*8)*64 + lk*8;
#pragma unroll
  for (int jn = 0; jn < 8; ++jn) {
    bf16x8 o;
#pragma unroll
    for (int jk = 0; jk < 8; ++jk) {
      o[jk] = (bf16)f[jk][jn >> 2][jn & 3];
    }
    *(bf16x8*)(dp + (long long)jn*64) = o;
  }
}

// ---------- fused: all-weight transpose+convert + x convert/column-sum (3136 blocks) ----------
__global__ __launch_bounds__(256)
void wtrans_cvt(const float* __restrict__ Wq, const float* __restrict__ Wk,
                const float* __restrict__ Wv, const float* __restrict__ Wo,
                const float* __restrict__ W1, const float* __restrict__ W2,
                bf16* __restrict__ wT, bf16* __restrict__ w1T, bf16* __restrict__ w2T,
                const float* __restrict__ x, bf16* __restrict__ xbf, float* __restrict__ part) {
  int zb = blockIdx.x;
  if (zb >= 3072) {                    // ---- cvt_xsum part ----
    int blk = zb - 3072;               // 64 = 8 batches x 8 chunks
    int b = blk >> 3, ch = blk & 7;
    int t = threadIdx.x;
    float s0 = 0.f, s1 = 0.f, s2 = 0.f, s3 = 0.f;
    long long base4 = ((long long)(b*CS + ch*32))*CD / 4;
#pragma unroll 4
    for (int r = 0; r < 32; ++r) {
      long long i4 = base4 + (long long)r*(CD/4) + t;
      float4 v = ((const float4*)x)[i4];
      bf16x4 o; o[0] = (bf16)v.x; o[1] = (bf16)v.y; o[2] = (bf16)v.z; o[3] = (bf16)v.w;
      ((bf16x4*)xbf)[i4] = o;
      s0 += v.x; s1 += v.y; s2 += v.z; s3 += v.w;
    }
    float4 sv; sv.x = s0; sv.y = s1; sv.z = s2; sv.w = s3;
    ((float4*)(part + (long long)blk*CD))[t] = sv;
    return;
  }
  const float* src; bf16* d; int rows, cols, btk, btn;
  if (zb < 1024) {                     // Wq/Wk/Wv/Wo: 16 mats of [1024][1024], 8x8 blocks each
    int m = zb >> 6, bt = zb & 63; int e = m >> 2; int which = m & 3;
    src = ((which == 0) ? Wq : (which == 1) ? Wk : (which == 2) ? Wv : Wo) + (long long)e*DD;
    d = wT + (long long)m*DD; rows = 1024; cols = 1024;
    btk = bt >> 3; btn = bt & 7;
  } else if (zb < 2048) {              // W1: 4 mats of [1024][4096], 8x32 blocks each
    int z2 = zb - 1024; int e = z2 >> 8; int bt = z2 & 255;
    src = W1 + (long long)e*DFF; d = w1T + (long long)e*DFF;
    rows = 1024; cols = 4096; btk = bt >> 5; btn = bt & 31;
  } else {                             // W2: 4 mats of [4096][1024], 32x8 blocks each
    int z3 = zb - 2048; int e = z3 >> 8; int bt = z3 & 255;
    src = W2 + (long long)e*DFF; d = w2T + (long long)e*DFF;
    rows = 4096; cols = 1024; btk = bt >> 3; btn = bt & 7;
  }
  wtile_trans(src, d, rows, cols, btk, btn);
}

// ---------- fused gating: 32 dot-pairs (reg partials + shfl reduce) + serial gating on t0 ----------
__global__ __launch_bounds__(256)
void gate_fused(const float* __restrict__ part, const float* __restrict__ wg,
                const float* __restrict__ wn, const float* __restrict__ noise,
                float* __restrict__ gates, int* __restrict__ eact, int* __restrict__ pairBE,
                int* __restrict__ batchPair, float* __restrict__ loss_out) {
  int t = threadIdx.x;
  float4 wgv[4], wnv[4];
  float xv[CB][4];
#pragma unroll
  for (int k = 0; k < 4; ++k) {
    int d = t + k*256;
    wgv[k] = ((const float4*)wg)[d];   // wg[d][e], e=0..3
    wnv[k] = ((const float4*)wn)[d];
#pragma unroll
    for (int b = 0; b < CB; ++b) {
      float s = 0.f;
#pragma unroll
      for (int c = 0; c < 8; ++c) s += part[(long long)(b*8 + c)*CD + d];
      xv[b][k] = s;
    }
  }
  __shared__ float red[4][64];
  __shared__ float sCR[64];            // [0..31] clean, [32..63] raw
  int lane = t & 63, wv = t >> 6;
#pragma unroll
  for (int b = 0; b < CB; ++b) {
#pragma unroll
    for (int e = 0; e < CE; ++e) {
      float s1 = 0.f, s2 = 0.f;
#pragma unroll
      for (int k = 0; k < 4; ++k) {
        const float* g  = (const float*)&wgv[k];
        const float* nn = (const float*)&wnv[k];
        s1 += xv[b][k]*g[e];
        s2 += xv[b][k]*nn[e];
      }
      for (int off = 32; off; off >>= 1) { s1 += __shfl_xor(s1, off); s2 += __shfl_xor(s2, off); }
      if (lane == 0) { red[wv][b*4 + e] = s1; red[wv][32 + b*4 + e] = s2; }
    }
  }
  __syncthreads();
  if (t < 64) sCR[t] = red[0][t] + red[1][t] + red[2][t] + red[3][t];
  __syncthreads();
  if (t != 0) return;
  const float* clean = sCR;
  const float* raw   = sCR + 32;
  float imp[CE] = {0,0,0,0}, load[CE] = {0,0,0,0};
  int act[CE] = {0,0,0,0};
  for (int b = 0; b < CB; ++b) {
    float cl[CE], sd[CE], ny[CE];
    for (int e = 0; e < CE; ++e) {
      cl[e] = clean[b*CE + e];
      float rw = raw[b*CE + e];
      float sp = fmaxf(rw, 0.f) + log1pf(expf(-fabsf(rw)));   // stable softplus
      sd[e] = sp + 0.01f;
      ny[e] = cl[e] + noise[b*CE + e]*sd[e];
    }
    int idx[CE] = {0,1,2,3};
    for (int a = 0; a < 3; ++a) {            // selection sort desc, stable
      int best = a;
      for (int c = a + 1; c < 4; ++c) if (ny[idx[c]] > ny[idx[best]]) best = c;
      int tt = idx[a]; idx[a] = idx[best]; idx[best] = tt;
    }
    float l0 = ny[idx[0]], l1 = ny[idx[1]], l2 = ny[idx[2]];
    float e1 = expf(l1 - l0);
    float g0 = 1.f/(1.f + e1), g1v = e1/(1.f + e1);
    for (int e = 0; e < CE; ++e) gates[b*CE + e] = 0.f;
    gates[b*CE + idx[0]] = g0; gates[b*CE + idx[1]] = g1v;
    imp[idx[0]] += g0; imp[idx[1]] += g1v;
    act[idx[0]] = 1; act[idx[1]] = 1;
    for (int e = 0; e < CE; ++e) {
      bool is_in = ny[e] > l2;
      float thr = is_in ? l2 : l1;
      float zz = (cl[e] - thr) / sd[e];
      load[e] += 0.5f * erfcf(-zz * 0.70710678118654752440f);
    }
  }
  int pe2p[CB][CE];
  int pc = 0;
  for (int e = 0; e < CE; ++e)
    for (int b = 0; b < CB; ++b)
      if (gates[b*CE + e] != 0.f) { pairBE[pc] = b | (e << 8); pe2p[b][e] = pc; ++pc; }
  for (int b = 0; b < CB; ++b) {
    int s = 0;
    for (int e = 0; e < CE; ++e)
      if (gates[b*CE + e] != 0.f) batchPair[2*b + (s++)] = pe2p[b][e];
  }
  float m1 = 0.f, m2 = 0.f;
  for (int e = 0; e < CE; ++e) { m1 += imp[e]; m2 += load[e]; }
  m1 *= 0.25f; m2 *= 0.25f;
  float v1 = 0.f, v2 = 0.f;
  for (int e = 0; e < CE; ++e) { float d1 = imp[e]-m1, d2 = load[e]-m2; v1 += d1*d1; v2 += d2*d2; }
  v1 *= (1.f/3.f); v2 *= (1.f/3.f);
  loss_out[0] = 0.01f * (v1/(m1*m1 + 1e-10f) + v2/(m2*m2 + 1e-10f));
  for (int e = 0; e < CE; ++e) eact[e] = act[e];
}

// v (compact slot 2, [pair][s][(h,hd)]) -> vT ([pair][h][hd][s])
__global__ __launch_bounds__(256)
void transpose_v(const bf16* __restrict__ qkvC, bf16* __restrict__ vTb) {
  int z = blockIdx.x; int p = z >> 4, h = z & 15;
  int w = threadIdx.x >> 6, lane = threadIdx.x & 63;
  int ln = lane >> 3, lk = lane & 7;
  const bf16* v = qkvC + 2*PSD + ((long long)(p*CS + w*64 + ln*8))*CD + h*CHD + lk*8;
  bf16x8 in[8];
#pragma unroll
  for (int j = 0; j < 8; ++j) in[j] = *(const bf16x8*)(v + (long long)j*CD);
  bf16* vt = vTb + ((long long)(p*CH + h)*CHD + lk*8)*CS + w*64 + ln*8;
#pragma unroll
  for (int dn = 0; dn < 8; ++dn) {
    bf16x8 o;
#pragma unroll
    for (int j = 0; j < 8; ++j) o[j] = in[j][dn];
    *(bf16x8*)(vt + (long long)dn*CS) = o;
  }
}

// ---------- async staging (global_load_lds width=16, XOR-swizzled on the global side) ----------
__device__ __forceinline__ void cp16(const bf16* g, bf16* l) {
  __builtin_amdgcn_global_load_lds((const __attribute__((address_space(1))) void*)g,
                                   (__attribute__((address_space(3))) void*)l, 16, 0, 0);
}

// stage R x 64 bf16 tile with NT threads
template<int R, int W, int NT>
__device__ __forceinline__ void stageN(const bf16* __restrict__ src, int ld, bf16* dst) {
  constexpr int W8 = W/8;
  int t = threadIdx.x;
  int l = t & 63, wid = t >> 6;
#pragma unroll
  for (int i = 0; i < (R*W8)/NT; ++i) {
    int idb = i*NT + wid*64;          // wave-uniform LDS base (chunk units)
    int id = idb + l;
    int row = id / W8, sl = id % W8;
    int gc = sl ^ (row & 7);          // XOR self-inverse
    cp16(src + (long long)row*ld + gc*8, dst + (long long)idb*8);
  }
}

// ---------- fused flash attention: block per (head, pair, q-tile); causal compute skipping ----------
__global__ __launch_bounds__(256)
void attn_fused(const bf16* __restrict__ qkvC, const bf16* __restrict__ vTb,
                bf16* __restrict__ aoC) {
  int h = blockIdx.x, p = blockIdx.y, qt = blockIdx.z;
  const bf16* qp = qkvC + (long long)(p*CS)*CD + h*CHD;
  const bf16* kp = qp + PSD;
  const bf16* vt = vTb + (long long)(p*CH + h)*CHD*CS;
  bf16* aop = aoC + (long long)(p*CS)*CD + h*CHD;

  __shared__ bf16 Ps[64*264];
  __shared__ float smaxL[64*4], ssumL[64*4], Lrow[64];

  int t = threadIdx.x, w = t >> 6, lane = t & 63, lr = lane & 15, quad = lane >> 4;

  floatx4 accs[4][4] = {};
  if (w <= qt) {                       // waves beyond qt have fully-masked columns
#pragma unroll
    for (int kk = 0; kk < 2; ++kk) {
      int c = kk*4 + quad;
      bf16x8 af[4], bfr[4];
#pragma unroll
      for (int i = 0; i < 4; ++i) {
        af[i]  = *(const bf16x8*)(qp + (long long)(qt*64 + i*16 + lr)*CD + c*8);
        bfr[i] = *(const bf16x8*)(kp + (long long)(w*64  + i*16 + lr)*CD + c*8);
      }
#pragma unroll
      for (int i = 0; i < 4; ++i)
#pragma unroll
        for (int j = 0; j < 4; ++j)
          accs[i][j] = __builtin_amdgcn_mfma_f32_16x16x32_bf16(af[i], bfr[j], accs[i][j], 0, 0, 0);
    }
  }
  float rmax[4][4];
#pragma unroll
  for (int i = 0; i < 4; ++i)
#pragma unroll
    for (int r = 0; r < 4; ++r) {
      int qrow = qt*64 + i*16 + quad*4 + r;
      float m = -3.0e38f;
#pragma unroll
      for (int j = 0; j < 4; ++j) {
        int kcol = w*64 + j*16 + lr;
        float s = accs[i][j][r]*0.125f;
        s = (kcol <= qrow) ? s : -3.0e38f;
        accs[i][j][r] = s;
        m = fmaxf(m, s);
      }
      rmax[i][r] = m;
    }
#pragma unroll
  for (int off = 1; off <= 8; off <<= 1)
#pragma unroll
    for (int i = 0; i < 4; ++i)
#pragma unroll
      for (int r = 0; r < 4; ++r) rmax[i][r] = fmaxf(rmax[i][r], __shfl_xor(rmax[i][r], off));
  if (lr == 0)
#pragma unroll
    for (int i = 0; i < 4; ++i)
#pragma unroll
      for (int r = 0; r < 4; ++r) smaxL[(i*16 + quad*4 + r)*4 + w] = rmax[i][r];
  __syncthreads();
  float rsum[4][4];
#pragma unroll
  for (int i = 0; i < 4; ++i)
#pragma unroll
    for (int r = 0; r < 4; ++r) {
      floatx4 mv = *(const floatx4*)&smaxL[(i*16 + quad*4 + r)*4];
      float M = fmaxf(fmaxf(mv[0], mv[1]), fmaxf(mv[2], mv[3]));
      float srow = 0.f;
#pragma unroll
      for (int j = 0; j < 4; ++j) {
        float pp = __expf(accs[i][j][r] - M);
        accs[i][j][r] = pp;
        srow += pp;
      }
      rsum[i][r] = srow;
    }
#pragma unroll
  for (int off = 1; off <= 8; off <<= 1)
#pragma unroll
    for (int i = 0; i < 4; ++i)
#pragma unroll
      for (int r = 0; r < 4; ++r) rsum[i][r] += __shfl_xor(rsum[i][r], off);
  if (lr == 0)
#pragma unroll
    for (int i = 0; i < 4; ++i)
#pragma unroll
      for (int r = 0; r < 4; ++r) ssumL[(i*16 + quad*4 + r)*4 + w] = rsum[i][r];
  __syncthreads();
  if (w == 0 && lr == 0) {
#pragma unroll
    for (int i = 0; i < 4; ++i)
#pragma unroll
      for (int r = 0; r < 4; ++r) {
        int m = i*16 + quad*4 + r;
        floatx4 sv = *(const floatx4*)&ssumL[m*4];
        Lrow[m] = sv[0] + sv[1] + sv[2] + sv[3];
      }
  }
  if (w <= qt) {                       // only valid columns are ever read back
#pragma unroll
    for (int i = 0; i < 4; ++i)
#pragma unroll
      for (int j = 0; j < 4; ++j)
#pragma unroll
        for (int r = 0; r < 4; ++r)
          Ps[(i*16 + quad*4 + r)*264 + w*64 + j*16 + lr] = (bf16)accs[i][j][r];
  }
  __syncthreads();
  floatx4 acco[4] = {};
  int ksMax = (qt + 1)*2;              // chunks c = ks*4+quad < (qt+1)*8  <=> s < (qt+1)*64
  for (int ks = 0; ks < ksMax; ++ks) {
    int c = ks*4 + quad;
    bf16x8 ap = *(const bf16x8*)(Ps + (w*16 + lr)*264 + c*8);
#pragma unroll
    for (int j = 0; j < 4; ++j) {
      bf16x8 bv = *(const bf16x8*)(vt + (long long)(j*16 + lr)*CS + c*8);
      acco[j] = __builtin_amdgcn_mfma_f32_16x16x32_bf16(ap, bv, acco[j], 0, 0, 0);
    }
  }
#pragma unroll
  for (int r = 0; r < 4; ++r) {
    int orow = w*16 + quad*4 + r;
    float inv = 1.f / Lrow[orow];
#pragma unroll
    for (int j = 0; j < 4; ++j)
      aop[(long long)(qt*64 + orow)*CD + j*16 + lr] = (bf16)(acco[j][r]*inv);
  }
}

// ---------- layernorms (vectorized) ----------
__global__ __launch_bounds__(256)
void ln1_kernel(const float* __restrict__ x, const float* __restrict__ PbF,
                const float* __restrict__ gamma, const float* __restrict__ beta,
                float* __restrict__ h, bf16* __restrict__ hbf, const int* __restrict__ pairBE) {
  int row = blockIdx.x;                     // 0..4095 compact
  int pbe = pairBE[row >> 8]; int pb = pbe & 255, pe = pbe >> 8;
  int t = threadIdx.x;
  float4 a = ((const float4*)(x + ((long long)pb*CS + (row & 255))*CD))[t];
  float4 b = ((const float4*)(PbF + (long long)row*CD))[t];
  float4 c = ((const float4*)(PbF + PSD + (long long)row*CD))[t];
  float v0 = a.x + b.x + c.x, v1 = a.y + b.y + c.y;
  float v2 = a.z + b.z + c.z, v3 = a.w + b.w + c.w;
  float s  = v0 + v1 + v2 + v3;
  float s2 = v0*v0 + v1*v1 + v2*v2 + v3*v3;
  int lane = t & 63, wave = t >> 6;
  for (int off = 32; off; off >>= 1) { s += __shfl_xor(s, off); s2 += __shfl_xor(s2, off); }
  __shared__ float red[8];
  if (lane == 0) { red[wave*2] = s; red[wave*2 + 1] = s2; }
  __syncthreads();
  s  = red[0] + red[2] + red[4] + red[6];
  s2 = red[1] + red[3] + red[5] + red[7];
  float mean = s * (1.f/CD);
  float rstd = rsqrtf(s2*(1.f/CD) - mean*mean + 1e-5f);
  float4 gm = ((const float4*)(gamma + (long long)pe*CD))[t];
  float4 bt = ((const float4*)(beta  + (long long)pe*CD))[t];
  float4 o;
  o.x = (v0 - mean)*rstd*gm.x + bt.x;
  o.y = (v1 - mean)*rstd*gm.y + bt.y;
  o.z = (v2 - mean)*rstd*gm.z + bt.z;
  o.w = (v3 - mean)*rstd*gm.w + bt.w;
  ((float4*)(h + (long long)row*CD))[t] = o;
  bf16x4 ob; ob[0] = (bf16)o.x; ob[1] = (bf16)o.y; ob[2] = (bf16)o.z; ob[3] = (bf16)o.w;
  ((bf16x4*)(hbf + (long long)row*CD))[t] = ob;
}

__global__ __launch_bounds__(256)
void ln2y_kernel(const float* __restrict__ h, const bf16* __restrict__ PbB,
                 const float* __restrict__ gamma, const float* __restrict__ beta,
                 float* __restrict__ y, const float* __restrict__ gates,
                 const int* __restrict__ pairBE, const int* __restrict__ batchPair) {
  int row = blockIdx.x;                     // 0..2047 = b*256 + s
  int b = row >> 8, sIdx = row & 255;
  int p0 = batchPair[2*b], p1 = batchPair[2*b + 1];
  int e0 = pairBE[p0] >> 8, e1 = pairBE[p1] >> 8;
  float gv0 = gates[b*CE + e0], gv1 = gates[b*CE + e1];
  long long r0 = (long long)p0*CS + sIdx, r1 = (long long)p1*CS + sIdx;
  int t = threadIdx.x;
  float4 a = ((const float4*)(h + r0*CD))[t];
  float4 c = ((const float4*)(h + r1*CD))[t];
#pragma unroll
  for (int k = 0; k < 4; ++k) {
    bf16x4 pa = ((const bf16x4*)(PbB + (long long)k*PSD + r0*CD))[t];
    bf16x4 pc = ((const bf16x4*)(PbB + (long long)k*PSD + r1*CD))[t];
    a.x += (float)pa[0]; a.y += (float)pa[1]; a.z += (float)pa[2]; a.w += (float)pa[3];
    c.x += (float)pc[0]; c.y += (float)pc[1]; c.z += (float)pc[2]; c.w += (float)pc[3];
  }
  float sA = a.x + a.y + a.z + a.w;
  float sA2 = a.x*a.x + a.y*a.y + a.z*a.z + a.w*a.w;
  float sB = c.x + c.y + c.z + c.w;
  float sB2 = c.x*c.x + c.y*c.y + c.z*c.z + c.w*c.w;
  int lane = t & 63, wave = t >> 6;
  for (int off = 32; off; off >>= 1) {
    sA += __shfl_xor(sA, off); sA2 += __shfl_xor(sA2, off);
    sB += __shfl_xor(sB, off); sB2 += __shfl_xor(sB2, off);
  }
  __shared__ float red[16];
  if (lane == 0) { red[wave*4] = sA; red[wave*4+1] = sA2; red[wave*4+2] = sB; red[wave*4+3] = sB2; }
  __syncthreads();
  sA  = red[0] + red[4] + red[8]  + red[12];
  sA2 = red[1] + red[5] + red[9]  + red[13];
  sB  = red[2] + red[6] + red[10] + red[14];
  sB2 = red[3] + red[7] + red[11] + red[15];
  float mA = sA*(1.f/CD), mB = sB*(1.f/CD);
  float rsA = rsqrtf(sA2*(1.f/CD) - mA*mA + 1e-5f);
  float rsB = rsqrtf(sB2*(1.f/CD) - mB*mB + 1e-5f);
  float4 gm0 = ((const float4*)(gamma + (long long)e0*CD))[t];
  float4 bt0 = ((const float4*)(beta  + (long long)e0*CD))[t];
  float4 gm1 = ((const float4*)(gamma + (long long)e1*CD))[t];
  float4 bt1 = ((const float4*)(beta  + (long long)e1*CD))[t];
  float4 o;
  o.x = gv0*((a.x - mA)*rsA*gm0.x + bt0.x) + gv1*((c.x - mB)*rsB*gm1.x + bt1.x);
  o.y = gv0*((a.y - mA)*rsA*gm0.y + bt0.y) + gv1*((c.y - mB)*rsB*gm1.y + bt1.y);
  o.z = gv0*((a.z - mA)*rsA*gm0.z + bt0.z) + gv1*((c.z - mB)*rsB*gm1.z + bt1.z);
  o.w = gv0*((a.w - mA)*rsA*gm0.w + bt0.w) + gv1*((c.w - mB)*rsB*gm1.w + bt1.w);
  constexpr float EF = 2.2204460492503131e-16f;
  o.x = (o.x == 0.f) ? EF : o.x;  o.y = (o.y == 0.f) ? EF : o.y;
  o.z = (o.z == 0.f) ? EF : o.z;  o.w = (o.w == 0.f) ? EF : o.w;
  ((float4*)(y + (long long)row*CD))[t] = o;
}

// ---------- MFMA GEMM on compact pairs:  C[M,N] = A[M,K] * Wt  (Wt k-tile-blocked [kt][n][64]) ----------
// 256x256 tile, 512 threads (8 waves, 2m x 4n), BK=64, double-buffered LDS with
// counted vmcnt (round-7 certified protocol). B-tiles are CONTIGUOUS 32KB blocks.
enum { EPI_BF16 = 0, EPI_F32 = 1, EPI_BRELU = 2, EPI_BIASBF16 = 3 };

template<int EPI, int KS, bool A_BATCH>
__global__ __launch_bounds__(512, 2)
void gemm_nt(const bf16* __restrict__ A, const bf16* __restrict__ Bt, void* __restrict__ Cv,
             int K /*per split*/, int lda, int nTot /*B matrix N width*/, int ldc,
             long long oBe, long long oBmat, long long oCmat, long long oCk,
             const float* __restrict__ bias, long long biasStride,
             const int* __restrict__ pairBE) {
  constexpr int BM = 256, BN = 256;
  int z = blockIdx.z;
  int zk = z % KS, mat = z / KS;
  // XCD y-chunk swizzle (bijective; nwg % 8 == 0 for all launches here)
  int gx = gridDim.x;
  int nwg = gx * gridDim.y;
  int lin = blockIdx.x + gx*blockIdx.y;
  int nl  = (lin & 7)*(nwg >> 3) + (lin >> 3);
  int m0 = (nl % gx) * BM, n0 = (nl / gx) * BN;
  int pbe = pairBE[m0 >> 8]; int pb = pbe & 255, pe = pbe >> 8;
  const bf16* Ab = A + (A_BATCH ? ((long long)pb*CS + (m0 & 255))*lda : (long long)m0*lda)
                     + (long long)zk*K;
  // B base: k-tile-blocked layout [kt][nTot][64]; this split starts at tile zk*(K/64)
  const long long tileStride = (long long)nTot*64;
  const bf16* Bb = Bt + (long long)pe*oBe + (long long)mat*oBmat
                      + (long long)(zk*(K/64))*tileStride + (long long)n0*64;
  long long coff = (long long)mat*oCmat + (long long)zk*oCk;

  __shared__ bf16 As[2][BM*64];
  __shared__ bf16 Bs[2][BN*64];

  int wave = threadIdx.x >> 6;
  int lane = threadIdx.x & 63;
  int wm = wave >> 2, wn = wave & 3;   // 2 x 4 wave grid; per-wave output 128m x 64n
  int lr = lane & 15;
  int quad = lane >> 4;

  floatx4 acc[8][4] = {};

  int nt = K / 64;
  stageN<BM, 64, 512>(Ab, lda, As[0]);
  stageN<BN, 64, 512>(Bb, 64, Bs[0]);
  for (int t = 0; t < nt; ++t) {
    int cur = t & 1;
    if (t + 1 < nt) {
      stageN<BM, 64, 512>(Ab + (t+1)*64, lda, As[cur ^ 1]);
      stageN<BN, 64, 512>(Bb + (long long)(t+1)*tileStride, 64, Bs[cur ^ 1]);
      asm volatile("s_waitcnt vmcnt(8)" ::: "memory");   // tile t landed; t+1 in flight
    } else {
      asm volatile("s_waitcnt vmcnt(0)" ::: "memory");
    }
    __builtin_amdgcn_s_barrier();
    asm volatile("" ::: "memory");     // fence: no LDS reads hoist above the barrier
#pragma unroll
    for (int kk = 0; kk < 2; ++kk) {
      int c = kk*4 + quad;
      bf16x8 af[8], bfr[4];
#pragma unroll
      for (int i = 0; i < 8; ++i) {
        int m = wm*128 + i*16 + lr;
        af[i] = *(const bf16x8*)(As[cur] + m*64 + ((c ^ (m & 7))*8));
      }
#pragma unroll
      for (int j = 0; j < 4; ++j) {
        int n = wn*64 + j*16 + lr;
        bfr[j] = *(const bf16x8*)(Bs[cur] + n*64 + ((c ^ (n & 7))*8));
      }
#pragma unroll
      for (int i = 0; i < 8; ++i)
#pragma unroll
        for (int j = 0; j < 4; ++j)
          acc[i][j] = __builtin_amdgcn_mfma_f32_16x16x32_bf16(af[i], bfr[j], acc[i][j], 0, 0, 0);
    }
    __builtin_amdgcn_s_barrier();
    asm volatile("" ::: "memory");     // fence: next iter's stage can't hoist above
  }

#pragma unroll
  for (int j = 0; j < 4; ++j) {
    int col = n0 + wn*64 + j*16 + lr;
    float bv = 0.f;
    if constexpr (EPI == EPI_BRELU || EPI == EPI_BIASBF16)
      if (zk == 0) bv = bias[(long long)pe*biasStride + col];
#pragma unroll
    for (int i = 0; i < 8; ++i) {
#pragma unroll
      for (int r = 0; r < 4; ++r) {
        int row = m0 + wm*128 + i*16 + quad*4 + r;
        float v = acc[i][j][r] + bv;
        long long idx = coff + (long long)row*ldc + col;
        if constexpr (EPI == EPI_BF16)          ((bf16*)Cv)[idx] = (bf16)v;
        else if constexpr (EPI == EPI_F32)      ((float*)Cv)[idx] = v;
        else if constexpr (EPI == EPI_BRELU)    ((bf16*)Cv)[idx] = (bf16)fmaxf(v, 0.f);
        else                                    ((bf16*)Cv)[idx] = (bf16)v;
      }
    }
  }
}

// ---------- launch ----------
extern "C" void kernel_launch(void* const* d_in, const int* in_sizes, int n_in,
                              void* d_out, int out_size, void* d_ws, size_t ws_size,
                              hipStream_t stream) {
  const float* x       = (const float*)d_in[0];
  const float* noise   = (const float*)d_in[2];
  const float* w_gate  = (const float*)d_in[3];
  const float* w_noise = (const float*)d_in[4];
  const float* Wq      = (const float*)d_in[5];
  const float* Wk      = (const float*)d_in[6];
  const float* Wv      = (const float*)d_in[7];
  const float* Wo      = (const float*)d_in[8];
  const float* W1      = (const float*)d_in[9];
  const float* b1      = (const float*)d_in[10];
  const float* W2      = (const float*)d_in[11];
  const float* b2      = (const float*)d_in[12];
  const float* g1      = (const float*)d_in[13];
  const float* be1     = (const float*)d_in[14];
  const float* g2      = (const float*)d_in[15];
  const float* be2     = (const float*)d_in[16];

  char* ws = (char*)d_ws;
  float* y    = (float*)d_out;
  float* loss = y + (size_t)BSD;

  float* part  = (float*)(ws + OFF_PART);
  float* gates = (float*)(ws + OFF_GATES);
  int*   eact  = (int*)  (ws + OFF_EACT);
  int*   pairBE= (int*)  (ws + OFF_PBE);
  int*   batchPair = (int*)(ws + OFF_BP);
  bf16*  xbf   = (bf16*) (ws + OFF_XBF);
  bf16*  wT    = (bf16*) (ws + OFF_WT);
  bf16*  w1T   = (bf16*) (ws + OFF_W1T);
  bf16*  w2T   = (bf16*) (ws + OFF_W2T);
  bf16*  qkvC  = (bf16*) (ws + OFF_QKV);
  bf16*  aoC   = (bf16*) (ws + OFF_AO);
  bf16*  f1    = (bf16*) (ws + OFF_F1);
  bf16*  vTb   = (bf16*) (ws + OFF_VT);
  float* PbF   = (float*)(ws + OFF_PB);
  bf16*  PbB   = (bf16*) (ws + OFF_PB);
  float* h     = (float*)(ws + OFF_H);
  bf16*  hbf   = (bf16*) (ws + OFF_HBF);

  // all-weight transpose (k-tile-blocked dest) + x convert/colsum
  wtrans_cvt<<<3136, 256, 0, stream>>>(Wq, Wk, Wv, Wo, W1, W2, wT, w1T, w2T, x, xbf, part);
  gate_fused<<<1, 256, 0, stream>>>(part, w_gate, w_noise, noise, gates, eact, pairBE, batchPair, loss);

  // q,k,v = x @ {Wq,Wk,Wv}  (compact M = 16 pairs x 256)
  gemm_nt<EPI_BF16, 1, true><<<dim3(16, 4, 3), 512, 0, stream>>>(
      xbf, wT, qkvC, 1024, 1024, 1024, 1024,
      4*DD, DD, PSD, 0, nullptr, 0, pairBE);

  transpose_v<<<256, 256, 0, stream>>>(qkvC, vTb);

  // fused attention: (head, pair, q-tile), causal skipping
  attn_fused<<<dim3(CH, 16, 4), 256, 0, stream>>>(qkvC, vTb, aoC);

  // o = ao @ Wo, split-K=2 -> f32 partials
  gemm_nt<EPI_F32, 2, false><<<dim3(16, 4, 2), 512, 0, stream>>>(
      aoC, wT + 3*DD, PbF, 512, 1024, 1024, 1024,
      4*DD, 0, 0, PSD, nullptr, 0, pairBE);

  // h = LN(x + o)
  ln1_kernel<<<4096, 256, 0, stream>>>(x, PbF, g1, be1, h, hbf, pairBE);

  // f1 = relu(h @ W1 + b1)   (f1 overlays qkv+ao)
  gemm_nt<EPI_BRELU, 1, false><<<dim3(16, 16, 1), 512, 0, stream>>>(
      hbf, w1T, f1, 1024, 1024, 4096, 4096,
      DFF, 0, 0, 0, b1, CFF, pairBE);

  // f2 = f1 @ W2 + b2, split-K=4 -> bf16 partials
  gemm_nt<EPI_BIASBF16, 4, false><<<dim3(16, 4, 4), 512, 0, stream>>>(
      f1, w2T, PbB, 1024, 4096, 1024, 1024,
      DFF, 0, 0, PSD, b2, CD, pairBE);

  // y = epsfill( sum of gate * LN(h + f2) over the batch's 2 active pairs )
  ln2y_kernel<<<2048, 256, 0, stream>>>(h, PbB, g2, be2, y, gates, pairBE, batchPair);
}

// Round 13
// 466.263 us; speedup vs baseline: 1.1056x; 1.1056x over previous
//
#include <hip/hip_runtime.h>
#include <hip/hip_bf16.h>

typedef __bf16 bf16;
typedef __attribute__((ext_vector_type(4))) __bf16 bf16x4;
typedef __attribute__((ext_vector_type(8))) __bf16 bf16x8;
typedef __attribute__((ext_vector_type(4))) float floatx4;

constexpr int CB = 8, CS = 256, CD = 1024, CH = 16, CE = 4, CFF = 4096, CHD = 64;
constexpr long long DD  = 1048576;     // D*D
constexpr long long DFF = 4194304;     // D*FF
constexpr long long BSD = 2097152;     // B*S*D
constexpr long long PSD = 4194304;     // 16 pairs * 256 rows * 1024 (compact activation elems)

// ---------- workspace layout (bytes) ----------
constexpr size_t OFF_PART = 0;          // 64*1024 f32 (x column-sum partials)
constexpr size_t OFF_CLEAN= 262144;     // 32 f
constexpr size_t OFF_RAW  = 262272;     // 32 f
constexpr size_t OFF_GATES= 262400;     // 32 f
constexpr size_t OFF_EACT = 262528;     // 4 int
constexpr size_t OFF_PBE  = 262592;     // 16 int: pair -> b | (e<<8)
constexpr size_t OFF_BP   = 262656;     // 16 int: batch -> 2 pair indices
constexpr size_t OFF_XBF  = 263168;     // BSD bf16
constexpr size_t OFF_WT   = OFF_XBF + (size_t)BSD*2;    // 16*DD bf16 (q,k,v,o x 4e)
constexpr size_t OFF_W1T  = OFF_WT  + (size_t)16*DD*2;  // 4*DFF bf16
constexpr size_t OFF_W2T  = OFF_W1T + (size_t)4*DFF*2;  // 4*DFF bf16
constexpr size_t OFF_QKV  = OFF_W2T + (size_t)4*DFF*2;  // 3*PSD bf16 (compact q,k,v)
constexpr size_t OFF_AO   = OFF_QKV + (size_t)3*PSD*2;  // PSD bf16
constexpr size_t OFF_F1   = OFF_QKV;                    // ALIAS: f1 (PSD*4 bf16) over qkv+ao (dead by FF1)
constexpr size_t OFF_PB   = OFF_AO  + (size_t)PSD*2;    // 2*PSD f32 (Wo partials) / 4*PSD bf16 (FF2 partials)
constexpr size_t OFF_VT   = OFF_PB;                     // ALIAS: vT (PSD bf16), dead before Wo writes PbF
constexpr size_t OFF_H    = OFF_PB  + (size_t)2*PSD*4;  // PSD f32
constexpr size_t OFF_HBF  = OFF_H   + (size_t)PSD*4;    // PSD bf16

// ---------- shared micro-transpose body: 2x2 wave super-tile, 8k x 8n per lane ----------
// Row-major dest d[n][k] (r7-certified layout).
__device__ __forceinline__ void wtile_trans(const float* __restrict__ src, bf16* __restrict__ d,
                                            int rows, int cols, int btk, int btn) {
  int w = threadIdx.x >> 6;
  int tk = btk*2 + (w & 1);           // waves 0,1: adjacent k, same n -> 256B write chunks
  int tn = btn*2 + (w >> 1);
  int lane = threadIdx.x & 63;
  int ln = lane >> 3, lk = lane & 7;  // lane = ln*8 + lk (lk fast -> contiguous k on store)
  int k0 = tk*64, n0 = tn*64;
  const float* s = src + (long long)(k0 + lk*8)*cols + n0 + ln*8;
  floatx4 f[8][2];
#pragma unroll
  for (int j = 0; j < 8; ++j) {
    f[j][0] = __builtin_nontemporal_load((const floatx4*)(s + (long long)j*cols));
    f[j][1] = __builtin_nontemporal_load((const floatx4*)(s + (long long)j*cols + 4));
  }
  bf16* dp = d + (long long)(n0 + ln*8)*rows + k0 + lk*8;
#pragma unroll
  for (int jn = 0; jn < 8; ++jn) {
    bf16x8 o;
#pragma unroll
    for (int jk = 0; jk < 8; ++jk) {
      o[jk] = (bf16)f[jk][jn >> 2][jn & 3];
    }
    *(bf16x8*)(dp + (long long)jn*rows) = o;
  }
}

// ---------- fused: all-weight transpose+convert + x convert/column-sum (3136 blocks) ----------
__global__ __launch_bounds__(256)
void wtrans_cvt(const float* __restrict__ Wq, const float* __restrict__ Wk,
                const float* __restrict__ Wv, const float* __restrict__ Wo,
                const float* __restrict__ W1, const float* __restrict__ W2,
                bf16* __restrict__ wT, bf16* __restrict__ w1T, bf16* __restrict__ w2T,
                const float* __restrict__ x, bf16* __restrict__ xbf, float* __restrict__ part) {
  int zb = blockIdx.x;
  if (zb >= 3072) {                    // ---- cvt_xsum part ----
    int blk = zb - 3072;               // 64 = 8 batches x 8 chunks
    int b = blk >> 3, ch = blk & 7;
    int t = threadIdx.x;
    float s0 = 0.f, s1 = 0.f, s2 = 0.f, s3 = 0.f;
    long long base4 = ((long long)(b*CS + ch*32))*CD / 4;
#pragma unroll 4
    for (int r = 0; r < 32; ++r) {
      long long i4 = base4 + (long long)r*(CD/4) + t;
      float4 v = ((const float4*)x)[i4];
      bf16x4 o; o[0] = (bf16)v.x; o[1] = (bf16)v.y; o[2] = (bf16)v.z; o[3] = (bf16)v.w;
      ((bf16x4*)xbf)[i4] = o;
      s0 += v.x; s1 += v.y; s2 += v.z; s3 += v.w;
    }
    float4 sv; sv.x = s0; sv.y = s1; sv.z = s2; sv.w = s3;
    ((float4*)(part + (long long)blk*CD))[t] = sv;
    return;
  }
  const float* src; bf16* d; int rows, cols, btk, btn;
  if (zb < 1024) {                     // Wq/Wk/Wv/Wo: 16 mats of [1024][1024], 8x8 blocks each
    int m = zb >> 6, bt = zb & 63; int e = m >> 2; int which = m & 3;
    src = ((which == 0) ? Wq : (which == 1) ? Wk : (which == 2) ? Wv : Wo) + (long long)e*DD;
    d = wT + (long long)m*DD; rows = 1024; cols = 1024;
    btk = bt >> 3; btn = bt & 7;
  } else if (zb < 2048) {              // W1: 4 mats of [1024][4096], 8x32 blocks each
    int z2 = zb - 1024; int e = z2 >> 8; int bt = z2 & 255;
    src = W1 + (long long)e*DFF; d = w1T + (long long)e*DFF;
    rows = 1024; cols = 4096; btk = bt >> 5; btn = bt & 31;
  } else {                             // W2: 4 mats of [4096][1024], 32x8 blocks each
    int z3 = zb - 2048; int e = z3 >> 8; int bt = z3 & 255;
    src = W2 + (long long)e*DFF; d = w2T + (long long)e*DFF;
    rows = 4096; cols = 1024; btk = bt >> 3; btn = bt & 7;
  }
  wtile_trans(src, d, rows, cols, btk, btn);
}

// ---------- gate dot-products: 32 blocks (one per (b,e)), parallel across CUs ----------
__global__ __launch_bounds__(256)
void gate_dots(const float* __restrict__ part, const float* __restrict__ wg,
               const float* __restrict__ wn, float* __restrict__ clean, float* __restrict__ raw) {
  int p = blockIdx.x, b = p >> 2, e = p & 3;
  int t = threadIdx.x;
  float s1 = 0.f, s2 = 0.f;
  for (int d = t; d < CD; d += 256) {
    float xv = 0.f;
#pragma unroll
    for (int c = 0; c < 8; ++c) xv += part[(long long)(b*8 + c)*CD + d];
    s1 += xv * wg[d*CE + e];
    s2 += xv * wn[d*CE + e];
  }
  for (int off = 32; off; off >>= 1) { s1 += __shfl_xor(s1, off); s2 += __shfl_xor(s2, off); }
  __shared__ float r1[4], r2[4];
  int lane = t & 63, w = t >> 6;
  if (lane == 0) { r1[w] = s1; r2[w] = s2; }
  __syncthreads();
  if (t == 0) { clean[p] = r1[0]+r1[1]+r1[2]+r1[3]; raw[p] = r2[0]+r2[1]+r2[2]+r2[3]; }
}

// ---------- gating: lane-parallel, LDS-resident tail (no serial global loads) ----------
// Lanes 0..31 (one per (b,e)): cl/sd/ny; lanes 0..7 (one per b): sort + softmax gates;
// lanes 0..31: load-probabilities (parallel erfcf); thread 0: compaction + loss from
// LDS only (global STORES only, no round-trips). Block = 1 wave (64 threads).
__global__ void gating_kernel(const float* __restrict__ clean, const float* __restrict__ raw,
                              const float* __restrict__ noise, float* __restrict__ gates,
                              int* __restrict__ eact, int* __restrict__ pairBE,
                              int* __restrict__ batchPair, float* __restrict__ loss_out) {
  int t = threadIdx.x;
  __shared__ float sCl[CB][CE], sSd[CB][CE], sNy[CB][CE];
  __shared__ float sG[CB][CE], sLoad[CB][CE];
  __shared__ float sL1[CB], sL2[CB];
  __shared__ int   sI0[CB], sI1[CB];
  if (t < 32) {
    int b = t >> 2, e = t & 3;
    float cl = clean[b*CE + e];
    float rw = raw[b*CE + e];
    float sp = fmaxf(rw, 0.f) + log1pf(expf(-fabsf(rw)));   // stable softplus
    float sd = sp + 0.01f;
    sCl[b][e] = cl; sSd[b][e] = sd;
    sNy[b][e] = cl + noise[b*CE + e]*sd;
  }
  __syncthreads();
  if (t < 8) {
    int b = t;
    float ny[CE] = {sNy[b][0], sNy[b][1], sNy[b][2], sNy[b][3]};
    int idx[CE] = {0,1,2,3};
    for (int a = 0; a < 3; ++a) {            // selection sort desc, stable
      int best = a;
      for (int c = a + 1; c < 4; ++c) if (ny[idx[c]] > ny[idx[best]]) best = c;
      int tt = idx[a]; idx[a] = idx[best]; idx[best] = tt;
    }
    float l0 = ny[idx[0]], l1 = ny[idx[1]], l2 = ny[idx[2]];
    float e1 = expf(l1 - l0);
    float g0 = 1.f/(1.f + e1), g1v = e1/(1.f + e1);
    for (int e = 0; e < CE; ++e) sG[b][e] = 0.f;
    sG[b][idx[0]] = g0; sG[b][idx[1]] = g1v;
    sL1[b] = l1; sL2[b] = l2;
    sI0[b] = idx[0]; sI1[b] = idx[1];
  }
  __syncthreads();
  if (t < 32) {
    int b = t >> 2, e = t & 3;
    bool is_in = sNy[b][e] > sL2[b];
    float thr = is_in ? sL2[b] : sL1[b];
    float zz = (sCl[b][e] - thr) / sSd[b][e];
    sLoad[b][e] = 0.5f * erfcf(-zz * 0.70710678118654752440f);
  }
  __syncthreads();
  if (t != 0) return;
  float imp[CE] = {0,0,0,0}, load[CE] = {0,0,0,0};
  int act[CE] = {0,0,0,0};
  for (int b = 0; b < CB; ++b) {
    for (int e = 0; e < CE; ++e) {
      gates[b*CE + e] = sG[b][e];            // global stores only (fire-and-forget)
      imp[e]  += sG[b][e];
      load[e] += sLoad[b][e];
    }
    act[sI0[b]] = 1; act[sI1[b]] = 1;
  }
  // compact pair list (sorted by expert, then batch) — always exactly 16 pairs
  int pe2p[CB][CE];
  int pc = 0;
  for (int e = 0; e < CE; ++e)
    for (int b = 0; b < CB; ++b)
      if (sG[b][e] != 0.f) { pairBE[pc] = b | (e << 8); pe2p[b][e] = pc; ++pc; }
  for (int b = 0; b < CB; ++b) {
    int s = 0;
    for (int e = 0; e < CE; ++e)
      if (sG[b][e] != 0.f) batchPair[2*b + (s++)] = pe2p[b][e];
  }
  float m1 = 0.f, m2 = 0.f;
  for (int e = 0; e < CE; ++e) { m1 += imp[e]; m2 += load[e]; }
  m1 *= 0.25f; m2 *= 0.25f;
  float v1 = 0.f, v2 = 0.f;
  for (int e = 0; e < CE; ++e) { float d1 = imp[e]-m1, d2 = load[e]-m2; v1 += d1*d1; v2 += d2*d2; }
  v1 *= (1.f/3.f); v2 *= (1.f/3.f);
  loss_out[0] = 0.01f * (v1/(m1*m1 + 1e-10f) + v2/(m2*m2 + 1e-10f));
  for (int e = 0; e < CE; ++e) eact[e] = act[e];
}

// v (compact slot 2, [pair][s][(h,hd)]) -> vT ([pair][h][hd][s])
__global__ __launch_bounds__(256)
void transpose_v(const bf16* __restrict__ qkvC, bf16* __restrict__ vTb) {
  int z = blockIdx.x; int p = z >> 4, h = z & 15;
  int w = threadIdx.x >> 6, lane = threadIdx.x & 63;
  int ln = lane >> 3, lk = lane & 7;
  const bf16* v = qkvC + 2*PSD + ((long long)(p*CS + w*64 + ln*8))*CD + h*CHD + lk*8;
  bf16x8 in[8];
#pragma unroll
  for (int j = 0; j < 8; ++j) in[j] = *(const bf16x8*)(v + (long long)j*CD);
  bf16* vt = vTb + ((long long)(p*CH + h)*CHD + lk*8)*CS + w*64 + ln*8;
#pragma unroll
  for (int dn = 0; dn < 8; ++dn) {
    bf16x8 o;
#pragma unroll
    for (int j = 0; j < 8; ++j) o[j] = in[j][dn];
    *(bf16x8*)(vt + (long long)dn*CS) = o;
  }
}

// ---------- async staging (global_load_lds width=16, XOR-swizzled on the global side) ----------
__device__ __forceinline__ void cp16(const bf16* g, bf16* l) {
  __builtin_amdgcn_global_load_lds((const __attribute__((address_space(1))) void*)g,
                                   (__attribute__((address_space(3))) void*)l, 16, 0, 0);
}

// stage R x 64 bf16 tile with NT threads
template<int R, int W, int NT>
__device__ __forceinline__ void stageN(const bf16* __restrict__ src, int ld, bf16* dst) {
  constexpr int W8 = W/8;
  int t = threadIdx.x;
  int l = t & 63, wid = t >> 6;
#pragma unroll
  for (int i = 0; i < (R*W8)/NT; ++i) {
    int idb = i*NT + wid*64;          // wave-uniform LDS base (chunk units)
    int id = idb + l;
    int row = id / W8, sl = id % W8;
    int gc = sl ^ (row & 7);          // XOR self-inverse
    cp16(src + (long long)row*ld + gc*8, dst + (long long)idb*8);
  }
}

// ---------- fused flash attention: block per (head, pair, q-tile); causal compute skipping ----------
__global__ __launch_bounds__(256)
void attn_fused(const bf16* __restrict__ qkvC, const bf16* __restrict__ vTb,
                bf16* __restrict__ aoC) {
  int h = blockIdx.x, p = blockIdx.y, qt = blockIdx.z;
  const bf16* qp = qkvC + (long long)(p*CS)*CD + h*CHD;
  const bf16* kp = qp + PSD;
  const bf16* vt = vTb + (long long)(p*CH + h)*CHD*CS;
  bf16* aop = aoC + (long long)(p*CS)*CD + h*CHD;

  __shared__ bf16 Ps[64*264];
  __shared__ float smaxL[64*4], ssumL[64*4], Lrow[64];

  int t = threadIdx.x, w = t >> 6, lane = t & 63, lr = lane & 15, quad = lane >> 4;

  floatx4 accs[4][4] = {};
  if (w <= qt) {                       // waves beyond qt have fully-masked columns
#pragma unroll
    for (int kk = 0; kk < 2; ++kk) {
      int c = kk*4 + quad;
      bf16x8 af[4], bfr[4];
#pragma unroll
      for (int i = 0; i < 4; ++i) {
        af[i]  = *(const bf16x8*)(qp + (long long)(qt*64 + i*16 + lr)*CD + c*8);
        bfr[i] = *(const bf16x8*)(kp + (long long)(w*64  + i*16 + lr)*CD + c*8);
      }
#pragma unroll
      for (int i = 0; i < 4; ++i)
#pragma unroll
        for (int j = 0; j < 4; ++j)
          accs[i][j] = __builtin_amdgcn_mfma_f32_16x16x32_bf16(af[i], bfr[j], accs[i][j], 0, 0, 0);
    }
  }
  float rmax[4][4];
#pragma unroll
  for (int i = 0; i < 4; ++i)
#pragma unroll
    for (int r = 0; r < 4; ++r) {
      int qrow = qt*64 + i*16 + quad*4 + r;
      float m = -3.0e38f;
#pragma unroll
      for (int j = 0; j < 4; ++j) {
        int kcol = w*64 + j*16 + lr;
        float s = accs[i][j][r]*0.125f;
        s = (kcol <= qrow) ? s : -3.0e38f;
        accs[i][j][r] = s;
        m = fmaxf(m, s);
      }
      rmax[i][r] = m;
    }
#pragma unroll
  for (int off = 1; off <= 8; off <<= 1)
#pragma unroll
    for (int i = 0; i < 4; ++i)
#pragma unroll
      for (int r = 0; r < 4; ++r) rmax[i][r] = fmaxf(rmax[i][r], __shfl_xor(rmax[i][r], off));
  if (lr == 0)
#pragma unroll
    for (int i = 0; i < 4; ++i)
#pragma unroll
      for (int r = 0; r < 4; ++r) smaxL[(i*16 + quad*4 + r)*4 + w] = rmax[i][r];
  __syncthreads();
  float rsum[4][4];
#pragma unroll
  for (int i = 0; i < 4; ++i)
#pragma unroll
    for (int r = 0; r < 4; ++r) {
      floatx4 mv = *(const floatx4*)&smaxL[(i*16 + quad*4 + r)*4];
      float M = fmaxf(fmaxf(mv[0], mv[1]), fmaxf(mv[2], mv[3]));
      float srow = 0.f;
#pragma unroll
      for (int j = 0; j < 4; ++j) {
        float pp = __expf(accs[i][j][r] - M);
        accs[i][j][r] = pp;
        srow += pp;
      }
      rsum[i][r] = srow;
    }
#pragma unroll
  for (int off = 1; off <= 8; off <<= 1)
#pragma unroll
    for (int i = 0; i < 4; ++i)
#pragma unroll
      for (int r = 0; r < 4; ++r) rsum[i][r] += __shfl_xor(rsum[i][r], off);
  if (lr == 0)
#pragma unroll
    for (int i = 0; i < 4; ++i)
#pragma unroll
      for (int r = 0; r < 4; ++r) ssumL[(i*16 + quad*4 + r)*4 + w] = rsum[i][r];
  __syncthreads();
  if (w == 0 && lr == 0) {
#pragma unroll
    for (int i = 0; i < 4; ++i)
#pragma unroll
      for (int r = 0; r < 4; ++r) {
        int m = i*16 + quad*4 + r;
        floatx4 sv = *(const floatx4*)&ssumL[m*4];
        Lrow[m] = sv[0] + sv[1] + sv[2] + sv[3];
      }
  }
  if (w <= qt) {                       // only valid columns are ever read back
#pragma unroll
    for (int i = 0; i < 4; ++i)
#pragma unroll
      for (int j = 0; j < 4; ++j)
#pragma unroll
        for (int r = 0; r < 4; ++r)
          Ps[(i*16 + quad*4 + r)*264 + w*64 + j*16 + lr] = (bf16)accs[i][j][r];
  }
  __syncthreads();
  floatx4 acco[4] = {};
  int ksMax = (qt + 1)*2;              // chunks c = ks*4+quad < (qt+1)*8  <=> s < (qt+1)*64
  for (int ks = 0; ks < ksMax; ++ks) {
    int c = ks*4 + quad;
    bf16x8 ap = *(const bf16x8*)(Ps + (w*16 + lr)*264 + c*8);
#pragma unroll
    for (int j = 0; j < 4; ++j) {
      bf16x8 bv = *(const bf16x8*)(vt + (long long)(j*16 + lr)*CS + c*8);
      acco[j] = __builtin_amdgcn_mfma_f32_16x16x32_bf16(ap, bv, acco[j], 0, 0, 0);
    }
  }
#pragma unroll
  for (int r = 0; r < 4; ++r) {
    int orow = w*16 + quad*4 + r;
    float inv = 1.f / Lrow[orow];
#pragma unroll
    for (int j = 0; j < 4; ++j)
      aop[(long long)(qt*64 + orow)*CD + j*16 + lr] = (bf16)(acco[j][r]*inv);
  }
}

// ---------- layernorms (vectorized) ----------
__global__ __launch_bounds__(256)
void ln1_kernel(const float* __restrict__ x, const float* __restrict__ PbF,
                const float* __restrict__ gamma, const float* __restrict__ beta,
                float* __restrict__ h, bf16* __restrict__ hbf, const int* __restrict__ pairBE) {
  int row = blockIdx.x;                     // 0..4095 compact
  int pbe = pairBE[row >> 8]; int pb = pbe & 255, pe = pbe >> 8;
  int t = threadIdx.x;
  float4 a = ((const float4*)(x + ((long long)pb*CS + (row & 255))*CD))[t];
  float4 b = ((const float4*)(PbF + (long long)row*CD))[t];
  float4 c = ((const float4*)(PbF + PSD + (long long)row*CD))[t];
  float v0 = a.x + b.x + c.x, v1 = a.y + b.y + c.y;
  float v2 = a.z + b.z + c.z, v3 = a.w + b.w + c.w;
  float s  = v0 + v1 + v2 + v3;
  float s2 = v0*v0 + v1*v1 + v2*v2 + v3*v3;
  int lane = t & 63, wave = t >> 6;
  for (int off = 32; off; off >>= 1) { s += __shfl_xor(s, off); s2 += __shfl_xor(s2, off); }
  __shared__ float red[8];
  if (lane == 0) { red[wave*2] = s; red[wave*2 + 1] = s2; }
  __syncthreads();
  s  = red[0] + red[2] + red[4] + red[6];
  s2 = red[1] + red[3] + red[5] + red[7];
  float mean = s * (1.f/CD);
  float rstd = rsqrtf(s2*(1.f/CD) - mean*mean + 1e-5f);
  float4 gm = ((const float4*)(gamma + (long long)pe*CD))[t];
  float4 bt = ((const float4*)(beta  + (long long)pe*CD))[t];
  float4 o;
  o.x = (v0 - mean)*rstd*gm.x + bt.x;
  o.y = (v1 - mean)*rstd*gm.y + bt.y;
  o.z = (v2 - mean)*rstd*gm.z + bt.z;
  o.w = (v3 - mean)*rstd*gm.w + bt.w;
  ((float4*)(h + (long long)row*CD))[t] = o;
  bf16x4 ob; ob[0] = (bf16)o.x; ob[1] = (bf16)o.y; ob[2] = (bf16)o.z; ob[3] = (bf16)o.w;
  ((bf16x4*)(hbf + (long long)row*CD))[t] = ob;
}

__global__ __launch_bounds__(256)
void ln2y_kernel(const float* __restrict__ h, const bf16* __restrict__ PbB,
                 const float* __restrict__ gamma, const float* __restrict__ beta,
                 float* __restrict__ y, const float* __restrict__ gates,
                 const int* __restrict__ pairBE, const int* __restrict__ batchPair) {
  int row = blockIdx.x;                     // 0..2047 = b*256 + s
  int b = row >> 8, sIdx = row & 255;
  int p0 = batchPair[2*b], p1 = batchPair[2*b + 1];
  int e0 = pairBE[p0] >> 8, e1 = pairBE[p1] >> 8;
  float gv0 = gates[b*CE + e0], gv1 = gates[b*CE + e1];
  long long r0 = (long long)p0*CS + sIdx, r1 = (long long)p1*CS + sIdx;
  int t = threadIdx.x;
  float4 a = ((const float4*)(h + r0*CD))[t];
  float4 c = ((const float4*)(h + r1*CD))[t];
#pragma unroll
  for (int k = 0; k < 4; ++k) {
    bf16x4 pa = ((const bf16x4*)(PbB + (long long)k*PSD + r0*CD))[t];
    bf16x4 pc = ((const bf16x4*)(PbB + (long long)k*PSD + r1*CD))[t];
    a.x += (float)pa[0]; a.y += (float)pa[1]; a.z += (float)pa[2]; a.w += (float)pa[3];
    c.x += (float)pc[0]; c.y += (float)pc[1]; c.z += (float)pc[2]; c.w += (float)pc[3];
  }
  float sA = a.x + a.y + a.z + a.w;
  float sA2 = a.x*a.x + a.y*a.y + a.z*a.z + a.w*a.w;
  float sB = c.x + c.y + c.z + c.w;
  float sB2 = c.x*c.x + c.y*c.y + c.z*c.z + c.w*c.w;
  int lane = t & 63, wave = t >> 6;
  for (int off = 32; off; off >>= 1) {
    sA += __shfl_xor(sA, off); sA2 += __shfl_xor(sA2, off);
    sB += __shfl_xor(sB, off); sB2 += __shfl_xor(sB2, off);
  }
  __shared__ float red[16];
  if (lane == 0) { red[wave*4] = sA; red[wave*4+1] = sA2; red[wave*4+2] = sB; red[wave*4+3] = sB2; }
  __syncthreads();
  sA  = red[0] + red[4] + red[8]  + red[12];
  sA2 = red[1] + red[5] + red[9]  + red[13];
  sB  = red[2] + red[6] + red[10] + red[14];
  sB2 = red[3] + red[7] + red[11] + red[15];
  float mA = sA*(1.f/CD), mB = sB*(1.f/CD);
  float rsA = rsqrtf(sA2*(1.f/CD) - mA*mA + 1e-5f);
  float rsB = rsqrtf(sB2*(1.f/CD) - mB*mB + 1e-5f);
  float4 gm0 = ((const float4*)(gamma + (long long)e0*CD))[t];
  float4 bt0 = ((const float4*)(beta  + (long long)e0*CD))[t];
  float4 gm1 = ((const float4*)(gamma + (long long)e1*CD))[t];
  float4 bt1 = ((const float4*)(beta  + (long long)e1*CD))[t];
  float4 o;
  o.x = gv0*((a.x - mA)*rsA*gm0.x + bt0.x) + gv1*((c.x - mB)*rsB*gm1.x + bt1.x);
  o.y = gv0*((a.y - mA)*rsA*gm0.y + bt0.y) + gv1*((c.y - mB)*rsB*gm1.y + bt1.y);
  o.z = gv0*((a.z - mA)*rsA*gm0.z + bt0.z) + gv1*((c.z - mB)*rsB*gm1.z + bt1.z);
  o.w = gv0*((a.w - mA)*rsA*gm0.w + bt0.w) + gv1*((c.w - mB)*rsB*gm1.w + bt1.w);
  constexpr float EF = 2.2204460492503131e-16f;
  o.x = (o.x == 0.f) ? EF : o.x;  o.y = (o.y == 0.f) ? EF : o.y;
  o.z = (o.z == 0.f) ? EF : o.z;  o.w = (o.w == 0.f) ? EF : o.w;
  ((float4*)(y + (long long)row*CD))[t] = o;
}

// ---------- MFMA GEMM on compact pairs:  C[M,N] = A[M,K] * Bt[N,K]^T ----------
// 256x256 tile, 512 threads (8 waves, 2m x 4n), BK=64, double-buffered LDS with
// counted vmcnt (round-7 certified template).
enum { EPI_BF16 = 0, EPI_F32 = 1, EPI_BRELU = 2, EPI_BIASBF16 = 3 };

template<int EPI, int KS, bool A_BATCH>
__global__ __launch_bounds__(512, 2)
void gemm_nt(const bf16* __restrict__ A, const bf16* __restrict__ Bt, void* __restrict__ Cv,
             int K /*per split*/, int lda, int ldb, int ldc,
             long long oBe, long long oBmat, long long oCmat, long long oCk,
             const float* __restrict__ bias, long long biasStride,
             const int* __restrict__ pairBE) {
  constexpr int BM = 256, BN = 256;
  int z = blockIdx.z;
  int zk = z % KS, mat = z / KS;
  // XCD y-chunk swizzle (bijective; nwg % 8 == 0 for all launches here)
  int gx = gridDim.x;
  int nwg = gx * gridDim.y;
  int lin = blockIdx.x + gx*blockIdx.y;
  int nl  = (lin & 7)*(nwg >> 3) + (lin >> 3);
  int m0 = (nl % gx) * BM, n0 = (nl / gx) * BN;
  int pbe = pairBE[m0 >> 8]; int pb = pbe & 255, pe = pbe >> 8;
  const bf16* Ab = A + (A_BATCH ? ((long long)pb*CS + (m0 & 255))*lda : (long long)m0*lda)
                     + (long long)zk*K;
  const bf16* Bb = Bt + (long long)pe*oBe + (long long)mat*oBmat + (long long)zk*K
                      + (long long)n0*ldb;
  long long coff = (long long)mat*oCmat + (long long)zk*oCk;

  __shared__ bf16 As[2][BM*64];
  __shared__ bf16 Bs[2][BN*64];

  int wave = threadIdx.x >> 6;
  int lane = threadIdx.x & 63;
  int wm = wave >> 2, wn = wave & 3;   // 2 x 4 wave grid; per-wave output 128m x 64n
  int lr = lane & 15;
  int quad = lane >> 4;

  floatx4 acc[8][4] = {};

  int nt = K / 64;
  stageN<BM, 64, 512>(Ab, lda, As[0]);
  stageN<BN, 64, 512>(Bb, ldb, Bs[0]);
  for (int t = 0; t < nt; ++t) {
    int cur = t & 1;
    if (t + 1 < nt) {
      stageN<BM, 64, 512>(Ab + (t+1)*64, lda, As[cur ^ 1]);
      stageN<BN, 64, 512>(Bb + (t+1)*64, ldb, Bs[cur ^ 1]);
      asm volatile("s_waitcnt vmcnt(8)" ::: "memory");   // tile t landed; t+1 in flight
    } else {
      asm volatile("s_waitcnt vmcnt(0)" ::: "memory");
    }
    __builtin_amdgcn_s_barrier();
    asm volatile("" ::: "memory");     // fence: no LDS reads hoist above the barrier
#pragma unroll
    for (int kk = 0; kk < 2; ++kk) {
      int c = kk*4 + quad;
      bf16x8 af[8], bfr[4];
#pragma unroll
      for (int i = 0; i < 8; ++i) {
        int m = wm*128 + i*16 + lr;
        af[i] = *(const bf16x8*)(As[cur] + m*64 + ((c ^ (m & 7))*8));
      }
#pragma unroll
      for (int j = 0; j < 4; ++j) {
        int n = wn*64 + j*16 + lr;
        bfr[j] = *(const bf16x8*)(Bs[cur] + n*64 + ((c ^ (n & 7))*8));
      }
#pragma unroll
      for (int i = 0; i < 8; ++i)
#pragma unroll
        for (int j = 0; j < 4; ++j)
          acc[i][j] = __builtin_amdgcn_mfma_f32_16x16x32_bf16(af[i], bfr[j], acc[i][j], 0, 0, 0);
    }
    __builtin_amdgcn_s_barrier();
    asm volatile("" ::: "memory");     // fence: next iter's stage can't hoist above
  }

#pragma unroll
  for (int j = 0; j < 4; ++j) {
    int col = n0 + wn*64 + j*16 + lr;
    float bv = 0.f;
    if constexpr (EPI == EPI_BRELU || EPI == EPI_BIASBF16)
      if (zk == 0) bv = bias[(long long)pe*biasStride + col];
#pragma unroll
    for (int i = 0; i < 8; ++i) {
#pragma unroll
      for (int r = 0; r < 4; ++r) {
        int row = m0 + wm*128 + i*16 + quad*4 + r;
        float v = acc[i][j][r] + bv;
        long long idx = coff + (long long)row*ldc + col;
        if constexpr (EPI == EPI_BF16)          ((bf16*)Cv)[idx] = (bf16)v;
        else if constexpr (EPI == EPI_F32)      ((float*)Cv)[idx] = v;
        else if constexpr (EPI == EPI_BRELU)    ((bf16*)Cv)[idx] = (bf16)fmaxf(v, 0.f);
        else                                    ((bf16*)Cv)[idx] = (bf16)v;
      }
    }
  }
}

// ---------- launch ----------
extern "C" void kernel_launch(void* const* d_in, const int* in_sizes, int n_in,
                              void* d_out, int out_size, void* d_ws, size_t ws_size,
                              hipStream_t stream) {
  const float* x       = (const float*)d_in[0];
  const float* noise   = (const float*)d_in[2];
  const float* w_gate  = (const float*)d_in[3];
  const float* w_noise = (const float*)d_in[4];
  const float* Wq      = (const float*)d_in[5];
  const float* Wk      = (const float*)d_in[6];
  const float* Wv      = (const float*)d_in[7];
  const float* Wo      = (const float*)d_in[8];
  const float* W1      = (const float*)d_in[9];
  const float* b1      = (const float*)d_in[10];
  const float* W2      = (const float*)d_in[11];
  const float* b2      = (const float*)d_in[12];
  const float* g1      = (const float*)d_in[13];
  const float* be1     = (const float*)d_in[14];
  const float* g2      = (const float*)d_in[15];
  const float* be2     = (const float*)d_in[16];

  char* ws = (char*)d_ws;
  float* y    = (float*)d_out;
  float* loss = y + (size_t)BSD;

  float* part  = (float*)(ws + OFF_PART);
  float* clean = (float*)(ws + OFF_CLEAN);
  float* raw   = (float*)(ws + OFF_RAW);
  float* gates = (float*)(ws + OFF_GATES);
  int*   eact  = (int*)  (ws + OFF_EACT);
  int*   pairBE= (int*)  (ws + OFF_PBE);
  int*   batchPair = (int*)(ws + OFF_BP);
  bf16*  xbf   = (bf16*) (ws + OFF_XBF);
  bf16*  wT    = (bf16*) (ws + OFF_WT);
  bf16*  w1T   = (bf16*) (ws + OFF_W1T);
  bf16*  w2T   = (bf16*) (ws + OFF_W2T);
  bf16*  qkvC  = (bf16*) (ws + OFF_QKV);
  bf16*  aoC   = (bf16*) (ws + OFF_AO);
  bf16*  f1    = (bf16*) (ws + OFF_F1);
  bf16*  vTb   = (bf16*) (ws + OFF_VT);
  float* PbF   = (float*)(ws + OFF_PB);
  bf16*  PbB   = (bf16*) (ws + OFF_PB);
  float* h     = (float*)(ws + OFF_H);
  bf16*  hbf   = (bf16*) (ws + OFF_HBF);

  // all-weight transpose + x convert/colsum (zero dependencies, launches first)
  wtrans_cvt<<<3136, 256, 0, stream>>>(Wq, Wk, Wv, Wo, W1, W2, wT, w1T, w2T, x, xbf, part);
  gate_dots<<<32, 256, 0, stream>>>(part, w_gate, w_noise, clean, raw);
  gating_kernel<<<1, 64, 0, stream>>>(clean, raw, noise, gates, eact, pairBE, batchPair, loss);

  // q,k,v = x @ {Wq,Wk,Wv}  (compact M = 16 pairs x 256)
  gemm_nt<EPI_BF16, 1, true><<<dim3(16, 4, 3), 512, 0, stream>>>(
      xbf, wT, qkvC, 1024, 1024, 1024, 1024,
      4*DD, DD, PSD, 0, nullptr, 0, pairBE);

  transpose_v<<<256, 256, 0, stream>>>(qkvC, vTb);

  // fused attention: (head, pair, q-tile), causal skipping
  attn_fused<<<dim3(CH, 16, 4), 256, 0, stream>>>(qkvC, vTb, aoC);

  // o = ao @ Wo, split-K=2 -> f32 partials
  gemm_nt<EPI_F32, 2, false><<<dim3(16, 4, 2), 512, 0, stream>>>(
      aoC, wT + 3*DD, PbF, 512, 1024, 1024, 1024,
      4*DD, 0, 0, PSD, nullptr, 0, pairBE);

  // h = LN(x + o)
  ln1_kernel<<<4096, 256, 0, stream>>>(x, PbF, g1, be1, h, hbf, pairBE);

  // f1 = relu(h @ W1 + b1)   (f1 overlays qkv+ao)
  gemm_nt<EPI_BRELU, 1, false><<<dim3(16, 16, 1), 512, 0, stream>>>(
      hbf, w1T, f1, 1024, 1024, 1024, 4096,
      DFF, 0, 0, 0, b1, CFF, pairBE);

  // f2 = f1 @ W2 + b2, split-K=4 -> bf16 partials
  gemm_nt<EPI_BIASBF16, 4, false><<<dim3(16, 4, 4), 512, 0, stream>>>(
      f1, w2T, PbB, 1024, 4096, 4096, 1024,
      DFF, 0, 0, PSD, b2, CD, pairBE);

  // y = epsfill( sum of gate * LN(h + f2) over the batch's 2 active pairs )
  ln2y_kernel<<<2048, 256, 0, stream>>>(h, PbB, g2, be2, y, gates, pairBE, batchPair);
}

// Round 14
// 459.322 us; speedup vs baseline: 1.1223x; 1.0151x over previous
//
#include <hip/hip_runtime.h>
#include <hip/hip_bf16.h>

typedef __bf16 bf16;
typedef __attribute__((ext_vector_type(4))) __bf16 bf16x4;
typedef __attribute__((ext_vector_type(8))) __bf16 bf16x8;
typedef __attribute__((ext_vector_type(4))) float floatx4;

constexpr int CB = 8, CS = 256, CD = 1024, CH = 16, CE = 4, CFF = 4096, CHD = 64;
constexpr long long DD  = 1048576;     // D*D
constexpr long long DFF = 4194304;     // D*FF
constexpr long long BSD = 2097152;     // B*S*D
constexpr long long PSD = 4194304;     // 16 pairs * 256 rows * 1024 (compact activation elems)

// ---------- workspace layout (bytes) ----------
constexpr size_t OFF_PART = 0;          // 64*1024 f32 (x column-sum partials)
constexpr size_t OFF_CLEAN= 262144;     // 32 f
constexpr size_t OFF_RAW  = 262272;     // 32 f
constexpr size_t OFF_GATES= 262400;     // 32 f
constexpr size_t OFF_EACT = 262528;     // 4 int
constexpr size_t OFF_PBE  = 262592;     // 16 int: pair -> b | (e<<8)
constexpr size_t OFF_BP   = 262656;     // 16 int: batch -> 2 pair indices
constexpr size_t OFF_XBF  = 263168;     // BSD bf16
constexpr size_t OFF_WT   = OFF_XBF + (size_t)BSD*2;    // 16*DD bf16 (q,k,v,o x 4e)
constexpr size_t OFF_W1T  = OFF_WT  + (size_t)16*DD*2;  // 4*DFF bf16
constexpr size_t OFF_W2T  = OFF_W1T + (size_t)4*DFF*2;  // 4*DFF bf16
constexpr size_t OFF_QKV  = OFF_W2T + (size_t)4*DFF*2;  // 3*PSD bf16 (compact q,k,v)
constexpr size_t OFF_AO   = OFF_QKV + (size_t)3*PSD*2;  // PSD bf16
constexpr size_t OFF_F1   = OFF_QKV;                    // ALIAS: f1 (PSD*4 bf16) over qkv+ao (dead by FF1)
constexpr size_t OFF_PB   = OFF_AO  + (size_t)PSD*2;    // 4*PSD bf16 (Wo partials / FF2 partials)
constexpr size_t OFF_VT   = OFF_PB;                     // ALIAS: vT (PSD bf16), dead before Wo writes PbB
constexpr size_t OFF_H    = OFF_PB  + (size_t)2*PSD*4;  // PSD f32
constexpr size_t OFF_HBF  = OFF_H   + (size_t)PSD*4;    // PSD bf16

// ---------- shared micro-transpose body: 2x2 wave super-tile, 8k x 8n per lane ----------
// Row-major dest d[n][k] (r7-certified layout).
__device__ __forceinline__ void wtile_trans(const float* __restrict__ src, bf16* __restrict__ d,
                                            int rows, int cols, int btk, int btn) {
  int w = threadIdx.x >> 6;
  int tk = btk*2 + (w & 1);           // waves 0,1: adjacent k, same n -> 256B write chunks
  int tn = btn*2 + (w >> 1);
  int lane = threadIdx.x & 63;
  int ln = lane >> 3, lk = lane & 7;  // lane = ln*8 + lk (lk fast -> contiguous k on store)
  int k0 = tk*64, n0 = tn*64;
  const float* s = src + (long long)(k0 + lk*8)*cols + n0 + ln*8;
  floatx4 f[8][2];
#pragma unroll
  for (int j = 0; j < 8; ++j) {
    f[j][0] = __builtin_nontemporal_load((const floatx4*)(s + (long long)j*cols));
    f[j][1] = __builtin_nontemporal_load((const floatx4*)(s + (long long)j*cols + 4));
  }
  bf16* dp = d + (long long)(n0 + ln*8)*rows + k0 + lk*8;
#pragma unroll
  for (int jn = 0; jn < 8; ++jn) {
    bf16x8 o;
#pragma unroll
    for (int jk = 0; jk < 8; ++jk) {
      o[jk] = (bf16)f[jk][jn >> 2][jn & 3];
    }
    *(bf16x8*)(dp + (long long)jn*rows) = o;
  }
}

// ---------- fused: all-weight transpose+convert + x convert/column-sum (3136 blocks) ----------
__global__ __launch_bounds__(256)
void wtrans_cvt(const float* __restrict__ Wq, const float* __restrict__ Wk,
                const float* __restrict__ Wv, const float* __restrict__ Wo,
                const float* __restrict__ W1, const float* __restrict__ W2,
                bf16* __restrict__ wT, bf16* __restrict__ w1T, bf16* __restrict__ w2T,
                const float* __restrict__ x, bf16* __restrict__ xbf, float* __restrict__ part) {
  int zb = blockIdx.x;
  if (zb >= 3072) {                    // ---- cvt_xsum part ----
    int blk = zb - 3072;               // 64 = 8 batches x 8 chunks
    int b = blk >> 3, ch = blk & 7;
    int t = threadIdx.x;
    float s0 = 0.f, s1 = 0.f, s2 = 0.f, s3 = 0.f;
    long long base4 = ((long long)(b*CS + ch*32))*CD / 4;
#pragma unroll 4
    for (int r = 0; r < 32; ++r) {
      long long i4 = base4 + (long long)r*(CD/4) + t;
      float4 v = ((const float4*)x)[i4];
      bf16x4 o; o[0] = (bf16)v.x; o[1] = (bf16)v.y; o[2] = (bf16)v.z; o[3] = (bf16)v.w;
      ((bf16x4*)xbf)[i4] = o;
      s0 += v.x; s1 += v.y; s2 += v.z; s3 += v.w;
    }
    float4 sv; sv.x = s0; sv.y = s1; sv.z = s2; sv.w = s3;
    ((float4*)(part + (long long)blk*CD))[t] = sv;
    return;
  }
  const float* src; bf16* d; int rows, cols, btk, btn;
  if (zb < 1024) {                     // Wq/Wk/Wv/Wo: 16 mats of [1024][1024], 8x8 blocks each
    int m = zb >> 6, bt = zb & 63; int e = m >> 2; int which = m & 3;
    src = ((which == 0) ? Wq : (which == 1) ? Wk : (which == 2) ? Wv : Wo) + (long long)e*DD;
    d = wT + (long long)m*DD; rows = 1024; cols = 1024;
    btk = bt >> 3; btn = bt & 7;
  } else if (zb < 2048) {              // W1: 4 mats of [1024][4096], 8x32 blocks each
    int z2 = zb - 1024; int e = z2 >> 8; int bt = z2 & 255;
    src = W1 + (long long)e*DFF; d = w1T + (long long)e*DFF;
    rows = 1024; cols = 4096; btk = bt >> 5; btn = bt & 31;
  } else {                             // W2: 4 mats of [4096][1024], 32x8 blocks each
    int z3 = zb - 2048; int e = z3 >> 8; int bt = z3 & 255;
    src = W2 + (long long)e*DFF; d = w2T + (long long)e*DFF;
    rows = 4096; cols = 1024; btk = bt >> 3; btn = bt & 7;
  }
  wtile_trans(src, d, rows, cols, btk, btn);
}

// ---------- gate dot-products: 32 blocks (one per (b,e)), parallel across CUs ----------
__global__ __launch_bounds__(256)
void gate_dots(const float* __restrict__ part, const float* __restrict__ wg,
               const float* __restrict__ wn, float* __restrict__ clean, float* __restrict__ raw) {
  int p = blockIdx.x, b = p >> 2, e = p & 3;
  int t = threadIdx.x;
  float s1 = 0.f, s2 = 0.f;
  for (int d = t; d < CD; d += 256) {
    float xv = 0.f;
#pragma unroll
    for (int c = 0; c < 8; ++c) xv += part[(long long)(b*8 + c)*CD + d];
    s1 += xv * wg[d*CE + e];
    s2 += xv * wn[d*CE + e];
  }
  for (int off = 32; off; off >>= 1) { s1 += __shfl_xor(s1, off); s2 += __shfl_xor(s2, off); }
  __shared__ float r1[4], r2[4];
  int lane = t & 63, w = t >> 6;
  if (lane == 0) { r1[w] = s1; r2[w] = s2; }
  __syncthreads();
  if (t == 0) { clean[p] = r1[0]+r1[1]+r1[2]+r1[3]; raw[p] = r2[0]+r2[1]+r2[2]+r2[3]; }
}

// ---------- gating: lane-parallel, LDS-resident tail (no serial global loads) ----------
__global__ void gating_kernel(const float* __restrict__ clean, const float* __restrict__ raw,
                              const float* __restrict__ noise, float* __restrict__ gates,
                              int* __restrict__ eact, int* __restrict__ pairBE,
                              int* __restrict__ batchPair, float* __restrict__ loss_out) {
  int t = threadIdx.x;
  __shared__ float sCl[CB][CE], sSd[CB][CE], sNy[CB][CE];
  __shared__ float sG[CB][CE], sLoad[CB][CE];
  __shared__ float sL1[CB], sL2[CB];
  __shared__ int   sI0[CB], sI1[CB];
  if (t < 32) {
    int b = t >> 2, e = t & 3;
    float cl = clean[b*CE + e];
    float rw = raw[b*CE + e];
    float sp = fmaxf(rw, 0.f) + log1pf(expf(-fabsf(rw)));   // stable softplus
    float sd = sp + 0.01f;
    sCl[b][e] = cl; sSd[b][e] = sd;
    sNy[b][e] = cl + noise[b*CE + e]*sd;
  }
  __syncthreads();
  if (t < 8) {
    int b = t;
    float ny[CE] = {sNy[b][0], sNy[b][1], sNy[b][2], sNy[b][3]};
    int idx[CE] = {0,1,2,3};
    for (int a = 0; a < 3; ++a) {            // selection sort desc, stable
      int best = a;
      for (int c = a + 1; c < 4; ++c) if (ny[idx[c]] > ny[idx[best]]) best = c;
      int tt = idx[a]; idx[a] = idx[best]; idx[best] = tt;
    }
    float l0 = ny[idx[0]], l1 = ny[idx[1]], l2 = ny[idx[2]];
    float e1 = expf(l1 - l0);
    float g0 = 1.f/(1.f + e1), g1v = e1/(1.f + e1);
    for (int e = 0; e < CE; ++e) sG[b][e] = 0.f;
    sG[b][idx[0]] = g0; sG[b][idx[1]] = g1v;
    sL1[b] = l1; sL2[b] = l2;
    sI0[b] = idx[0]; sI1[b] = idx[1];
  }
  __syncthreads();
  if (t < 32) {
    int b = t >> 2, e = t & 3;
    bool is_in = sNy[b][e] > sL2[b];
    float thr = is_in ? sL2[b] : sL1[b];
    float zz = (sCl[b][e] - thr) / sSd[b][e];
    sLoad[b][e] = 0.5f * erfcf(-zz * 0.70710678118654752440f);
  }
  __syncthreads();
  if (t != 0) return;
  float imp[CE] = {0,0,0,0}, load[CE] = {0,0,0,0};
  int act[CE] = {0,0,0,0};
  for (int b = 0; b < CB; ++b) {
    for (int e = 0; e < CE; ++e) {
      gates[b*CE + e] = sG[b][e];            // global stores only (fire-and-forget)
      imp[e]  += sG[b][e];
      load[e] += sLoad[b][e];
    }
    act[sI0[b]] = 1; act[sI1[b]] = 1;
  }
  // compact pair list (sorted by expert, then batch) — always exactly 16 pairs
  int pe2p[CB][CE];
  int pc = 0;
  for (int e = 0; e < CE; ++e)
    for (int b = 0; b < CB; ++b)
      if (sG[b][e] != 0.f) { pairBE[pc] = b | (e << 8); pe2p[b][e] = pc; ++pc; }
  for (int b = 0; b < CB; ++b) {
    int s = 0;
    for (int e = 0; e < CE; ++e)
      if (sG[b][e] != 0.f) batchPair[2*b + (s++)] = pe2p[b][e];
  }
  float m1 = 0.f, m2 = 0.f;
  for (int e = 0; e < CE; ++e) { m1 += imp[e]; m2 += load[e]; }
  m1 *= 0.25f; m2 *= 0.25f;
  float v1 = 0.f, v2 = 0.f;
  for (int e = 0; e < CE; ++e) { float d1 = imp[e]-m1, d2 = load[e]-m2; v1 += d1*d1; v2 += d2*d2; }
  v1 *= (1.f/3.f); v2 *= (1.f/3.f);
  loss_out[0] = 0.01f * (v1/(m1*m1 + 1e-10f) + v2/(m2*m2 + 1e-10f));
  for (int e = 0; e < CE; ++e) eact[e] = act[e];
}

// v (compact slot 2, [pair][s][(h,hd)]) -> vT ([pair][h][hd][s])
__global__ __launch_bounds__(256)
void transpose_v(const bf16* __restrict__ qkvC, bf16* __restrict__ vTb) {
  int z = blockIdx.x; int p = z >> 4, h = z & 15;
  int w = threadIdx.x >> 6, lane = threadIdx.x & 63;
  int ln = lane >> 3, lk = lane & 7;
  const bf16* v = qkvC + 2*PSD + ((long long)(p*CS + w*64 + ln*8))*CD + h*CHD + lk*8;
  bf16x8 in[8];
#pragma unroll
  for (int j = 0; j < 8; ++j) in[j] = *(const bf16x8*)(v + (long long)j*CD);
  bf16* vt = vTb + ((long long)(p*CH + h)*CHD + lk*8)*CS + w*64 + ln*8;
#pragma unroll
  for (int dn = 0; dn < 8; ++dn) {
    bf16x8 o;
#pragma unroll
    for (int j = 0; j < 8; ++j) o[j] = in[j][dn];
    *(bf16x8*)(vt + (long long)dn*CS) = o;
  }
}

// ---------- async staging (global_load_lds width=16, XOR-swizzled on the global side) ----------
__device__ __forceinline__ void cp16(const bf16* g, bf16* l) {
  __builtin_amdgcn_global_load_lds((const __attribute__((address_space(1))) void*)g,
                                   (__attribute__((address_space(3))) void*)l, 16, 0, 0);
}

// stage R x 64 bf16 tile with NT threads
template<int R, int W, int NT>
__device__ __forceinline__ void stageN(const bf16* __restrict__ src, int ld, bf16* dst) {
  constexpr int W8 = W/8;
  int t = threadIdx.x;
  int l = t & 63, wid = t >> 6;
#pragma unroll
  for (int i = 0; i < (R*W8)/NT; ++i) {
    int idb = i*NT + wid*64;          // wave-uniform LDS base (chunk units)
    int id = idb + l;
    int row = id / W8, sl = id % W8;
    int gc = sl ^ (row & 7);          // XOR self-inverse
    cp16(src + (long long)row*ld + gc*8, dst + (long long)idb*8);
  }
}

// ---------- fused flash attention: block per (head, pair, q-tile); causal compute skipping ----------
__global__ __launch_bounds__(256)
void attn_fused(const bf16* __restrict__ qkvC, const bf16* __restrict__ vTb,
                bf16* __restrict__ aoC) {
  int h = blockIdx.x, p = blockIdx.y, qt = blockIdx.z;
  const bf16* qp = qkvC + (long long)(p*CS)*CD + h*CHD;
  const bf16* kp = qp + PSD;
  const bf16* vt = vTb + (long long)(p*CH + h)*CHD*CS;
  bf16* aop = aoC + (long long)(p*CS)*CD + h*CHD;

  __shared__ bf16 Ps[64*264];
  __shared__ float smaxL[64*4], ssumL[64*4], Lrow[64];

  int t = threadIdx.x, w = t >> 6, lane = t & 63, lr = lane & 15, quad = lane >> 4;

  floatx4 accs[4][4] = {};
  if (w <= qt) {                       // waves beyond qt have fully-masked columns
#pragma unroll
    for (int kk = 0; kk < 2; ++kk) {
      int c = kk*4 + quad;
      bf16x8 af[4], bfr[4];
#pragma unroll
      for (int i = 0; i < 4; ++i) {
        af[i]  = *(const bf16x8*)(qp + (long long)(qt*64 + i*16 + lr)*CD + c*8);
        bfr[i] = *(const bf16x8*)(kp + (long long)(w*64  + i*16 + lr)*CD + c*8);
      }
#pragma unroll
      for (int i = 0; i < 4; ++i)
#pragma unroll
        for (int j = 0; j < 4; ++j)
          accs[i][j] = __builtin_amdgcn_mfma_f32_16x16x32_bf16(af[i], bfr[j], accs[i][j], 0, 0, 0);
    }
  }
  float rmax[4][4];
#pragma unroll
  for (int i = 0; i < 4; ++i)
#pragma unroll
    for (int r = 0; r < 4; ++r) {
      int qrow = qt*64 + i*16 + quad*4 + r;
      float m = -3.0e38f;
#pragma unroll
      for (int j = 0; j < 4; ++j) {
        int kcol = w*64 + j*16 + lr;
        float s = accs[i][j][r]*0.125f;
        s = (kcol <= qrow) ? s : -3.0e38f;
        accs[i][j][r] = s;
        m = fmaxf(m, s);
      }
      rmax[i][r] = m;
    }
#pragma unroll
  for (int off = 1; off <= 8; off <<= 1)
#pragma unroll
    for (int i = 0; i < 4; ++i)
#pragma unroll
      for (int r = 0; r < 4; ++r) rmax[i][r] = fmaxf(rmax[i][r], __shfl_xor(rmax[i][r], off));
  if (lr == 0)
#pragma unroll
    for (int i = 0; i < 4; ++i)
#pragma unroll
      for (int r = 0; r < 4; ++r) smaxL[(i*16 + quad*4 + r)*4 + w] = rmax[i][r];
  __syncthreads();
  float rsum[4][4];
#pragma unroll
  for (int i = 0; i < 4; ++i)
#pragma unroll
    for (int r = 0; r < 4; ++r) {
      floatx4 mv = *(const floatx4*)&smaxL[(i*16 + quad*4 + r)*4];
      float M = fmaxf(fmaxf(mv[0], mv[1]), fmaxf(mv[2], mv[3]));
      float srow = 0.f;
#pragma unroll
      for (int j = 0; j < 4; ++j) {
        float pp = __expf(accs[i][j][r] - M);
        accs[i][j][r] = pp;
        srow += pp;
      }
      rsum[i][r] = srow;
    }
#pragma unroll
  for (int off = 1; off <= 8; off <<= 1)
#pragma unroll
    for (int i = 0; i < 4; ++i)
#pragma unroll
      for (int r = 0; r < 4; ++r) rsum[i][r] += __shfl_xor(rsum[i][r], off);
  if (lr == 0)
#pragma unroll
    for (int i = 0; i < 4; ++i)
#pragma unroll
      for (int r = 0; r < 4; ++r) ssumL[(i*16 + quad*4 + r)*4 + w] = rsum[i][r];
  __syncthreads();
  if (w == 0 && lr == 0) {
#pragma unroll
    for (int i = 0; i < 4; ++i)
#pragma unroll
      for (int r = 0; r < 4; ++r) {
        int m = i*16 + quad*4 + r;
        floatx4 sv = *(const floatx4*)&ssumL[m*4];
        Lrow[m] = sv[0] + sv[1] + sv[2] + sv[3];
      }
  }
  if (w <= qt) {                       // only valid columns are ever read back
#pragma unroll
    for (int i = 0; i < 4; ++i)
#pragma unroll
      for (int j = 0; j < 4; ++j)
#pragma unroll
        for (int r = 0; r < 4; ++r)
          Ps[(i*16 + quad*4 + r)*264 + w*64 + j*16 + lr] = (bf16)accs[i][j][r];
  }
  __syncthreads();
  floatx4 acco[4] = {};
  int ksMax = (qt + 1)*2;              // chunks c = ks*4+quad < (qt+1)*8  <=> s < (qt+1)*64
  for (int ks = 0; ks < ksMax; ++ks) {
    int c = ks*4 + quad;
    bf16x8 ap = *(const bf16x8*)(Ps + (w*16 + lr)*264 + c*8);
#pragma unroll
    for (int j = 0; j < 4; ++j) {
      bf16x8 bv = *(const bf16x8*)(vt + (long long)(j*16 + lr)*CS + c*8);
      acco[j] = __builtin_amdgcn_mfma_f32_16x16x32_bf16(ap, bv, acco[j], 0, 0, 0);
    }
  }
#pragma unroll
  for (int r = 0; r < 4; ++r) {
    int orow = w*16 + quad*4 + r;
    float inv = 1.f / Lrow[orow];
#pragma unroll
    for (int j = 0; j < 4; ++j)
      aop[(long long)(qt*64 + orow)*CD + j*16 + lr] = (bf16)(acco[j][r]*inv);
  }
}

// ---------- layernorms (vectorized) ----------
// h = LN(x + sum of 4 bf16 Wo-partials); writes f32 + bf16 (compact rows)
__global__ __launch_bounds__(256)
void ln1_kernel(const float* __restrict__ x, const bf16* __restrict__ PbB,
                const float* __restrict__ gamma, const float* __restrict__ beta,
                float* __restrict__ h, bf16* __restrict__ hbf, const int* __restrict__ pairBE) {
  int row = blockIdx.x;                     // 0..4095 compact
  int pbe = pairBE[row >> 8]; int pb = pbe & 255, pe = pbe >> 8;
  int t = threadIdx.x;
  float4 a = ((const float4*)(x + ((long long)pb*CS + (row & 255))*CD))[t];
#pragma unroll
  for (int k = 0; k < 4; ++k) {
    bf16x4 pa = ((const bf16x4*)(PbB + (long long)k*PSD + (long long)row*CD))[t];
    a.x += (float)pa[0]; a.y += (float)pa[1]; a.z += (float)pa[2]; a.w += (float)pa[3];
  }
  float v0 = a.x, v1 = a.y, v2 = a.z, v3 = a.w;
  float s  = v0 + v1 + v2 + v3;
  float s2 = v0*v0 + v1*v1 + v2*v2 + v3*v3;
  int lane = t & 63, wave = t >> 6;
  for (int off = 32; off; off >>= 1) { s += __shfl_xor(s, off); s2 += __shfl_xor(s2, off); }
  __shared__ float red[8];
  if (lane == 0) { red[wave*2] = s; red[wave*2 + 1] = s2; }
  __syncthreads();
  s  = red[0] + red[2] + red[4] + red[6];
  s2 = red[1] + red[3] + red[5] + red[7];
  float mean = s * (1.f/CD);
  float rstd = rsqrtf(s2*(1.f/CD) - mean*mean + 1e-5f);
  float4 gm = ((const float4*)(gamma + (long long)pe*CD))[t];
  float4 bt = ((const float4*)(beta  + (long long)pe*CD))[t];
  float4 o;
  o.x = (v0 - mean)*rstd*gm.x + bt.x;
  o.y = (v1 - mean)*rstd*gm.y + bt.y;
  o.z = (v2 - mean)*rstd*gm.z + bt.z;
  o.w = (v3 - mean)*rstd*gm.w + bt.w;
  ((float4*)(h + (long long)row*CD))[t] = o;
  bf16x4 ob; ob[0] = (bf16)o.x; ob[1] = (bf16)o.y; ob[2] = (bf16)o.z; ob[3] = (bf16)o.w;
  ((bf16x4*)(hbf + (long long)row*CD))[t] = ob;
}

__global__ __launch_bounds__(256)
void ln2y_kernel(const float* __restrict__ h, const bf16* __restrict__ PbB,
                 const float* __restrict__ gamma, const float* __restrict__ beta,
                 float* __restrict__ y, const float* __restrict__ gates,
                 const int* __restrict__ pairBE, const int* __restrict__ batchPair) {
  int row = blockIdx.x;                     // 0..2047 = b*256 + s
  int b = row >> 8, sIdx = row & 255;
  int p0 = batchPair[2*b], p1 = batchPair[2*b + 1];
  int e0 = pairBE[p0] >> 8, e1 = pairBE[p1] >> 8;
  float gv0 = gates[b*CE + e0], gv1 = gates[b*CE + e1];
  long long r0 = (long long)p0*CS + sIdx, r1 = (long long)p1*CS + sIdx;
  int t = threadIdx.x;
  float4 a = ((const float4*)(h + r0*CD))[t];
  float4 c = ((const float4*)(h + r1*CD))[t];
#pragma unroll
  for (int k = 0; k < 4; ++k) {
    bf16x4 pa = ((const bf16x4*)(PbB + (long long)k*PSD + r0*CD))[t];
    bf16x4 pc = ((const bf16x4*)(PbB + (long long)k*PSD + r1*CD))[t];
    a.x += (float)pa[0]; a.y += (float)pa[1]; a.z += (float)pa[2]; a.w += (float)pa[3];
    c.x += (float)pc[0]; c.y += (float)pc[1]; c.z += (float)pc[2]; c.w += (float)pc[3];
  }
  float sA = a.x + a.y + a.z + a.w;
  float sA2 = a.x*a.x + a.y*a.y + a.z*a.z + a.w*a.w;
  float sB = c.x + c.y + c.z + c.w;
  float sB2 = c.x*c.x + c.y*c.y + c.z*c.z + c.w*c.w;
  int lane = t & 63, wave = t >> 6;
  for (int off = 32; off; off >>= 1) {
    sA += __shfl_xor(sA, off); sA2 += __shfl_xor(sA2, off);
    sB += __shfl_xor(sB, off); sB2 += __shfl_xor(sB2, off);
  }
  __shared__ float red[16];
  if (lane == 0) { red[wave*4] = sA; red[wave*4+1] = sA2; red[wave*4+2] = sB; red[wave*4+3] = sB2; }
  __syncthreads();
  sA  = red[0] + red[4] + red[8]  + red[12];
  sA2 = red[1] + red[5] + red[9]  + red[13];
  sB  = red[2] + red[6] + red[10] + red[14];
  sB2 = red[3] + red[7] + red[11] + red[15];
  float mA = sA*(1.f/CD), mB = sB*(1.f/CD);
  float rsA = rsqrtf(sA2*(1.f/CD) - mA*mA + 1e-5f);
  float rsB = rsqrtf(sB2*(1.f/CD) - mB*mB + 1e-5f);
  float4 gm0 = ((const float4*)(gamma + (long long)e0*CD))[t];
  float4 bt0 = ((const float4*)(beta  + (long long)e0*CD))[t];
  float4 gm1 = ((const float4*)(gamma + (long long)e1*CD))[t];
  float4 bt1 = ((const float4*)(beta  + (long long)e1*CD))[t];
  float4 o;
  o.x = gv0*((a.x - mA)*rsA*gm0.x + bt0.x) + gv1*((c.x - mB)*rsB*gm1.x + bt1.x);
  o.y = gv0*((a.y - mA)*rsA*gm0.y + bt0.y) + gv1*((c.y - mB)*rsB*gm1.y + bt1.y);
  o.z = gv0*((a.z - mA)*rsA*gm0.z + bt0.z) + gv1*((c.z - mB)*rsB*gm1.z + bt1.z);
  o.w = gv0*((a.w - mA)*rsA*gm0.w + bt0.w) + gv1*((c.w - mB)*rsB*gm1.w + bt1.w);
  constexpr float EF = 2.2204460492503131e-16f;
  o.x = (o.x == 0.f) ? EF : o.x;  o.y = (o.y == 0.f) ? EF : o.y;
  o.z = (o.z == 0.f) ? EF : o.z;  o.w = (o.w == 0.f) ? EF : o.w;
  ((float4*)(y + (long long)row*CD))[t] = o;
}

// ---------- MFMA GEMM on compact pairs:  C[M,N] = A[M,K] * Bt[N,K]^T ----------
// 256x256 tile, 512 threads (8 waves, 2m x 4n), BK=64, double-buffered LDS with
// counted vmcnt (round-7 certified template).
enum { EPI_BF16 = 0, EPI_F32 = 1, EPI_BRELU = 2, EPI_BIASBF16 = 3 };

template<int EPI, int KS, bool A_BATCH>
__global__ __launch_bounds__(512, 2)
void gemm_nt(const bf16* __restrict__ A, const bf16* __restrict__ Bt, void* __restrict__ Cv,
             int K /*per split*/, int lda, int ldb, int ldc,
             long long oBe, long long oBmat, long long oCmat, long long oCk,
             const float* __restrict__ bias, long long biasStride,
             const int* __restrict__ pairBE) {
  constexpr int BM = 256, BN = 256;
  int z = blockIdx.z;
  int zk = z % KS, mat = z / KS;
  // XCD y-chunk swizzle (bijective; nwg % 8 == 0 for all launches here)
  int gx = gridDim.x;
  int nwg = gx * gridDim.y;
  int lin = blockIdx.x + gx*blockIdx.y;
  int nl  = (lin & 7)*(nwg >> 3) + (lin >> 3);
  int m0 = (nl % gx) * BM, n0 = (nl / gx) * BN;
  int pbe = pairBE[m0 >> 8]; int pb = pbe & 255, pe = pbe >> 8;
  const bf16* Ab = A + (A_BATCH ? ((long long)pb*CS + (m0 & 255))*lda : (long long)m0*lda)
                     + (long long)zk*K;
  const bf16* Bb = Bt + (long long)pe*oBe + (long long)mat*oBmat + (long long)zk*K
                      + (long long)n0*ldb;
  long long coff = (long long)mat*oCmat + (long long)zk*oCk;

  __shared__ bf16 As[2][BM*64];
  __shared__ bf16 Bs[2][BN*64];

  int wave = threadIdx.x >> 6;
  int lane = threadIdx.x & 63;
  int wm = wave >> 2, wn = wave & 3;   // 2 x 4 wave grid; per-wave output 128m x 64n
  int lr = lane & 15;
  int quad = lane >> 4;

  floatx4 acc[8][4] = {};

  int nt = K / 64;
  stageN<BM, 64, 512>(Ab, lda, As[0]);
  stageN<BN, 64, 512>(Bb, ldb, Bs[0]);
  for (int t = 0; t < nt; ++t) {
    int cur = t & 1;
    if (t + 1 < nt) {
      stageN<BM, 64, 512>(Ab + (t+1)*64, lda, As[cur ^ 1]);
      stageN<BN, 64, 512>(Bb + (t+1)*64, ldb, Bs[cur ^ 1]);
      asm volatile("s_waitcnt vmcnt(8)" ::: "memory");   // tile t landed; t+1 in flight
    } else {
      asm volatile("s_waitcnt vmcnt(0)" ::: "memory");
    }
    __builtin_amdgcn_s_barrier();
    asm volatile("" ::: "memory");     // fence: no LDS reads hoist above the barrier
#pragma unroll
    for (int kk = 0; kk < 2; ++kk) {
      int c = kk*4 + quad;
      bf16x8 af[8], bfr[4];
#pragma unroll
      for (int i = 0; i < 8; ++i) {
        int m = wm*128 + i*16 + lr;
        af[i] = *(const bf16x8*)(As[cur] + m*64 + ((c ^ (m & 7))*8));
      }
#pragma unroll
      for (int j = 0; j < 4; ++j) {
        int n = wn*64 + j*16 + lr;
        bfr[j] = *(const bf16x8*)(Bs[cur] + n*64 + ((c ^ (n & 7))*8));
      }
#pragma unroll
      for (int i = 0; i < 8; ++i)
#pragma unroll
        for (int j = 0; j < 4; ++j)
          acc[i][j] = __builtin_amdgcn_mfma_f32_16x16x32_bf16(af[i], bfr[j], acc[i][j], 0, 0, 0);
    }
    __builtin_amdgcn_s_barrier();
    asm volatile("" ::: "memory");     // fence: next iter's stage can't hoist above
  }

#pragma unroll
  for (int j = 0; j < 4; ++j) {
    int col = n0 + wn*64 + j*16 + lr;
    float bv = 0.f;
    if constexpr (EPI == EPI_BRELU || EPI == EPI_BIASBF16)
      if (zk == 0) bv = bias[(long long)pe*biasStride + col];
#pragma unroll
    for (int i = 0; i < 8; ++i) {
#pragma unroll
      for (int r = 0; r < 4; ++r) {
        int row = m0 + wm*128 + i*16 + quad*4 + r;
        float v = acc[i][j][r] + bv;
        long long idx = coff + (long long)row*ldc + col;
        if constexpr (EPI == EPI_BF16)          ((bf16*)Cv)[idx] = (bf16)v;
        else if constexpr (EPI == EPI_F32)      ((float*)Cv)[idx] = v;
        else if constexpr (EPI == EPI_BRELU)    ((bf16*)Cv)[idx] = (bf16)fmaxf(v, 0.f);
        else                                    ((bf16*)Cv)[idx] = (bf16)v;
      }
    }
  }
}

// ---------- launch ----------
extern "C" void kernel_launch(void* const* d_in, const int* in_sizes, int n_in,
                              void* d_out, int out_size, void* d_ws, size_t ws_size,
                              hipStream_t stream) {
  const float* x       = (const float*)d_in[0];
  const float* noise   = (const float*)d_in[2];
  const float* w_gate  = (const float*)d_in[3];
  const float* w_noise = (const float*)d_in[4];
  const float* Wq      = (const float*)d_in[5];
  const float* Wk      = (const float*)d_in[6];
  const float* Wv      = (const float*)d_in[7];
  const float* Wo      = (const float*)d_in[8];
  const float* W1      = (const float*)d_in[9];
  const float* b1      = (const float*)d_in[10];
  const float* W2      = (const float*)d_in[11];
  const float* b2      = (const float*)d_in[12];
  const float* g1      = (const float*)d_in[13];
  const float* be1     = (const float*)d_in[14];
  const float* g2      = (const float*)d_in[15];
  const float* be2     = (const float*)d_in[16];

  char* ws = (char*)d_ws;
  float* y    = (float*)d_out;
  float* loss = y + (size_t)BSD;

  float* part  = (float*)(ws + OFF_PART);
  float* clean = (float*)(ws + OFF_CLEAN);
  float* raw   = (float*)(ws + OFF_RAW);
  float* gates = (float*)(ws + OFF_GATES);
  int*   eact  = (int*)  (ws + OFF_EACT);
  int*   pairBE= (int*)  (ws + OFF_PBE);
  int*   batchPair = (int*)(ws + OFF_BP);
  bf16*  xbf   = (bf16*) (ws + OFF_XBF);
  bf16*  wT    = (bf16*) (ws + OFF_WT);
  bf16*  w1T   = (bf16*) (ws + OFF_W1T);
  bf16*  w2T   = (bf16*) (ws + OFF_W2T);
  bf16*  qkvC  = (bf16*) (ws + OFF_QKV);
  bf16*  aoC   = (bf16*) (ws + OFF_AO);
  bf16*  f1    = (bf16*) (ws + OFF_F1);
  bf16*  vTb   = (bf16*) (ws + OFF_VT);
  bf16*  PbB   = (bf16*) (ws + OFF_PB);
  float* h     = (float*)(ws + OFF_H);
  bf16*  hbf   = (bf16*) (ws + OFF_HBF);

  // all-weight transpose + x convert/colsum (zero dependencies, launches first)
  wtrans_cvt<<<3136, 256, 0, stream>>>(Wq, Wk, Wv, Wo, W1, W2, wT, w1T, w2T, x, xbf, part);
  gate_dots<<<32, 256, 0, stream>>>(part, w_gate, w_noise, clean, raw);
  gating_kernel<<<1, 64, 0, stream>>>(clean, raw, noise, gates, eact, pairBE, batchPair, loss);

  // q,k,v = x @ {Wq,Wk,Wv}  (compact M = 16 pairs x 256)
  gemm_nt<EPI_BF16, 1, true><<<dim3(16, 4, 3), 512, 0, stream>>>(
      xbf, wT, qkvC, 1024, 1024, 1024, 1024,
      4*DD, DD, PSD, 0, nullptr, 0, pairBE);

  transpose_v<<<256, 256, 0, stream>>>(qkvC, vTb);

  // fused attention: (head, pair, q-tile), causal skipping
  attn_fused<<<dim3(CH, 16, 4), 256, 0, stream>>>(qkvC, vTb, aoC);

  // o = ao @ Wo, split-K=4 -> bf16 partials (256 blocks: full CU coverage)
  gemm_nt<EPI_BF16, 4, false><<<dim3(16, 4, 4), 512, 0, stream>>>(
      aoC, wT + 3*DD, PbB, 256, 1024, 1024, 1024,
      4*DD, 0, 0, PSD, nullptr, 0, pairBE);

  // h = LN(x + sum of 4 Wo partials)
  ln1_kernel<<<4096, 256, 0, stream>>>(x, PbB, g1, be1, h, hbf, pairBE);

  // f1 = relu(h @ W1 + b1)   (f1 overlays qkv+ao)
  gemm_nt<EPI_BRELU, 1, false><<<dim3(16, 16, 1), 512, 0, stream>>>(
      hbf, w1T, f1, 1024, 1024, 1024, 4096,
      DFF, 0, 0, 0, b1, CFF, pairBE);

  // f2 = f1 @ W2 + b2, split-K=4 -> bf16 partials
  gemm_nt<EPI_BIASBF16, 4, false><<<dim3(16, 4, 4), 512, 0, stream>>>(
      f1, w2T, PbB, 1024, 4096, 4096, 1024,
      DFF, 0, 0, PSD, b2, CD, pairBE);

  // y = epsfill( sum of gate * LN(h + f2) over the batch's 2 active pairs )
  ln2y_kernel<<<2048, 256, 0, stream>>>(h, PbB, g2, be2, y, gates, pairBE, batchPair);
}